// Round 7
// baseline (621.458 us; speedup 1.0000x reference)
//
#include <hip/hip_runtime.h>

#define N_NODES 50000
#define N_EDGES 800000
#define CCH 64
#define N_MIX 14

typedef __bf16 bf16x8 __attribute__((ext_vector_type(8)));
typedef __bf16 bf16x4 __attribute__((ext_vector_type(4)));
typedef float floatx4 __attribute__((ext_vector_type(4)));

__device__ __forceinline__ float leaky(float x) {
    return fmaxf(x, 0.2f * x);
}

// ---------------- weight prep --------------------------------------------
// Wt[k] : 64(out-col) x 256(in-dim) bf16, transposed, scale-folded.
//   j<64: g*w0*gcn_W ; j<128: g*w1*sage_Wl ;
//   j<192: g*w1*sage_Wr + I*(g*w3 + (k>=11 ? 0.25 : 0)) ; j<256: g*w2*gat_W
// g=0.25 for k>=9 (final mean folded); +0.25*I for k in {11,12,13} folds
// final_mean's 0.25*(s2+s3+s4) since those k's H-input IS s2/s3/s4.
__global__ void prep_weights(const float* __restrict__ alphas,
                             const float* __restrict__ gcn_W, const float* __restrict__ gcn_b,
                             const float* __restrict__ sage_Wl, const float* __restrict__ sage_Wr,
                             const float* __restrict__ sage_b, const float* __restrict__ gat_Wp,
                             const float* __restrict__ a_src, const float* __restrict__ a_dst,
                             const float* __restrict__ gat_b,
                             __bf16* __restrict__ Wt, float* __restrict__ bc,
                             float* __restrict__ vs, float* __restrict__ vd) {
    int k = blockIdx.x;
    __shared__ float w[5];
    if (threadIdx.x == 0) {
        float a[5], m = -1e30f, s = 0.f;
        for (int i = 0; i < 5; ++i) { a[i] = alphas[k * 5 + i]; m = fmaxf(m, a[i]); }
        for (int i = 0; i < 5; ++i) { a[i] = __expf(a[i] - m); s += a[i]; }
        for (int i = 0; i < 5; ++i) w[i] = a[i] / s;
    }
    __syncthreads();
    float gamma = (k >= 9) ? 0.25f : 1.0f;
    float w0 = gamma * w[0], w1 = gamma * w[1], w2 = gamma * w[2], w3 = gamma * w[3];
    float idext = (k >= 11) ? 0.25f : 0.f;
    for (int idx = threadIdx.x; idx < 64 * 256; idx += blockDim.x) {
        int c = idx >> 8, j = idx & 255;
        float v;
        if (j < 64)       v = w0 * gcn_W[k * 4096 + j * 64 + c];
        else if (j < 128) v = w1 * sage_Wl[k * 4096 + (j - 64) * 64 + c];
        else if (j < 192) {
            int jj = j - 128;
            v = w1 * sage_Wr[k * 4096 + jj * 64 + c];
            if (jj == c) v += w3 + idext;
        } else {
            v = w2 * gat_Wp[k * 4096 + (j - 192) * 64 + c];
        }
        Wt[(size_t)k * 16384 + idx] = (__bf16)v;
    }
    if (threadIdx.x < 64) {
        int r = threadIdx.x;
        bc[k * 64 + r] = gamma * (w[0] * gcn_b[k * 64 + r] + w[1] * sage_b[k * 64 + r] +
                                  w[2] * gat_b[k * 64 + r]);
        float s1 = 0.f, s2 = 0.f;
        for (int j = 0; j < 64; ++j) {
            float wv_ = gat_Wp[k * 4096 + r * 64 + j];
            s1 += wv_ * a_src[k * 64 + j];
            s2 += wv_ * a_dst[k * 64 + j];
        }
        vs[k * 64 + r] = s1;
        vd[k * 64 + r] = s2;
    }
}

__global__ void convert_bf16(const float4* __restrict__ src, __bf16* __restrict__ dst, int n4) {
    int i = blockIdx.x * blockDim.x + threadIdx.x;
    if (i < n4) {
        float4 v = src[i];
        dst[i * 4 + 0] = (__bf16)v.x;
        dst[i * 4 + 1] = (__bf16)v.y;
        dst[i * 4 + 2] = (__bf16)v.z;
        dst[i * 4 + 3] = (__bf16)v.w;
    }
}

// ---------------- CSR build ------------------------------------------------
__global__ void count_indeg(const int* __restrict__ ei, int* __restrict__ indeg) {
    int e = blockIdx.x * blockDim.x + threadIdx.x;
    if (e < N_EDGES) atomicAdd(&indeg[ei[N_EDGES + e]], 1);
}

#define NBLK 196  // ceil(50000/256)

__global__ __launch_bounds__(256) void deg_block_reduce(const int* __restrict__ indeg,
                                                        int* __restrict__ bsum) {
    int i = blockIdx.x * 256 + threadIdx.x;
    int v = (i < N_NODES) ? indeg[i] : 0;
#pragma unroll
    for (int off = 1; off < 64; off <<= 1) v += __shfl_xor(v, off, 64);
    __shared__ int ws_[4];
    if ((threadIdx.x & 63) == 0) ws_[threadIdx.x >> 6] = v;
    __syncthreads();
    if (threadIdx.x == 0) bsum[blockIdx.x] = ws_[0] + ws_[1] + ws_[2] + ws_[3];
}

__global__ __launch_bounds__(256) void scan_bsum(int* __restrict__ bsum, int* __restrict__ row_ptr) {
    __shared__ int s[256];
    int t = threadIdx.x;
    int v = (t < NBLK) ? bsum[t] : 0;
    s[t] = v;
    __syncthreads();
    for (int off = 1; off < 256; off <<= 1) {
        int tmp = (t >= off) ? s[t - off] : 0;
        __syncthreads();
        s[t] += tmp;
        __syncthreads();
    }
    if (t < NBLK) bsum[t] = s[t] - v;  // exclusive
    if (t == 0) row_ptr[N_NODES] = s[255];
}

__global__ __launch_bounds__(256) void scan_write(int* __restrict__ indeg,
                                                  const int* __restrict__ bsum,
                                                  int* __restrict__ row_ptr,
                                                  float* __restrict__ dinv,
                                                  float* __restrict__ cntf) {
    int i = blockIdx.x * 256 + threadIdx.x;
    int lane = threadIdx.x & 63, wv = threadIdx.x >> 6;
    int val = (i < N_NODES) ? indeg[i] : 0;
    int inc = val;
#pragma unroll
    for (int off = 1; off < 64; off <<= 1) {
        int t2 = __shfl_up(inc, off, 64);
        if (lane >= off) inc += t2;
    }
    __shared__ int wsum[4];
    if (lane == 63) wsum[wv] = inc;
    __syncthreads();
    int woff = 0;
    for (int j = 0; j < wv; ++j) woff += wsum[j];
    if (i < N_NODES) {
        row_ptr[i] = bsum[blockIdx.x] + woff + inc - val;
        dinv[i] = rsqrtf((float)(val + 1));
        cntf[i] = (float)(val > 0 ? val : 1);
        indeg[i] = 0;  // reuse as fill counter
    }
}

__global__ void fill_csr(const int* __restrict__ ei, const int* __restrict__ row_ptr,
                         int* __restrict__ fill_cnt, int* __restrict__ col_idx) {
    int e = blockIdx.x * blockDim.x + threadIdx.x;
    if (e < N_EDGES) {
        int d = ei[N_EDGES + e];
        int pos = row_ptr[d] + atomicAdd(&fill_cnt[d], 1);
        col_idx[pos] = ei[e];
    }
}

// ---------------- per-state GAT scores (stride 8 for vector loads) ---------
template <int NK>
__global__ __launch_bounds__(256) void score_kernel(const float* __restrict__ h,
                                                    const float* __restrict__ vs_all,
                                                    const float* __restrict__ vd_all,
                                                    unsigned kmap,
                                                    float* __restrict__ ssrcS,
                                                    float* __restrict__ sdstS) {
    int node = blockIdx.x * 4 + (threadIdx.x >> 6);
    int lane = threadIdx.x & 63;
    if (node >= N_NODES) return;
    float hv = h[(size_t)node * 64 + lane];
#pragma unroll
    for (int t = 0; t < NK; ++t) {
        int k = (kmap >> (4 * t)) & 15;
        float ps = hv * vs_all[k * 64 + lane];
        float pd = hv * vd_all[k * 64 + lane];
#pragma unroll
        for (int off = 1; off < 64; off <<= 1) {
            ps += __shfl_xor(ps, off, 64);
            pd += __shfl_xor(pd, off, 64);
        }
        if (lane == 0) {
            ssrcS[(size_t)node * 8 + t] = ps;
            sdstS[(size_t)node * 8 + t] = pd;
        }
    }
}

// ---------------- fused per-state gather: 8 nodes per wave -----------------
// sub = lane>>3 (node in wave), ln = lane&7. Each 8-lane group owns one node;
// lane ln covers channels 8*ln..8*ln+7 (bf16x8 = 16 B -> group covers the
// full 128-B row; a wave's load fetches 8 rows = 1 KB). Loop bounds are
// per-group (uniform within the 8 lanes) -> no cross-node degmax waste, and
// shfl sources are always active. Scores at stride 8 -> float4 loads.
// NK <= 4 keeps acc[NK][8] register pressure under the 128-VGPR cliff.
template <int NK>
__global__ __launch_bounds__(128, 4) void fused_gather(
    const __bf16* __restrict__ hb, const int* __restrict__ row_ptr,
    const int* __restrict__ col_idx, const float* __restrict__ dinv,
    const float* __restrict__ cntf, const float* __restrict__ ssrcS,
    const float* __restrict__ sdstS, int soff, int doGS,
    __bf16* __restrict__ aggG, __bf16* __restrict__ aggS, __bf16* __restrict__ A) {
    int wid = blockIdx.x * 2 + (threadIdx.x >> 6);
    int lane = threadIdx.x & 63;
    int sub = lane >> 3, ln = lane & 7;
    int node = wid * 8 + sub;  // grid exact: 3125 blocks * 16 nodes
    int beg = row_ptr[node], end = row_ptr[node + 1];

    float sd[NK], selfraw[NK];
    {
        float4 sv = *(const float4*)(ssrcS + (size_t)node * 8 + soff);
        float4 dvv = *(const float4*)(sdstS + (size_t)node * 8 + soff);
        float svv[4] = {sv.x, sv.y, sv.z, sv.w};
        float dvl[4] = {dvv.x, dvv.y, dvv.z, dvv.w};
#pragma unroll
        for (int t = 0; t < NK; ++t) {
            sd[t] = dvl[t];
            selfraw[t] = leaky(svv[t] + sd[t]);
        }
    }
    bf16x8 hsb = *(const bf16x8*)(hb + (size_t)node * 64 + ln * 8);
    float hs[8];
#pragma unroll
    for (int c = 0; c < 8; ++c) hs[c] = (float)hsb[c];

    // ---- pass A: per-k max over in-edges ----
    float m[NK];
#pragma unroll
    for (int t = 0; t < NK; ++t) m[t] = selfraw[t];
    for (int base = beg; base < end; base += 8) {
        int e = base + ln;
        if (e < end) {
            int c2 = col_idx[e];
            float4 sv = *(const float4*)(ssrcS + (size_t)c2 * 8 + soff);
            float svv[4] = {sv.x, sv.y, sv.z, sv.w};
#pragma unroll
            for (int t = 0; t < NK; ++t) m[t] = fmaxf(m[t], leaky(svv[t] + sd[t]));
        }
    }
#pragma unroll
    for (int t = 0; t < NK; ++t)
#pragma unroll
        for (int off = 1; off < 8; off <<= 1) m[t] = fmaxf(m[t], __shfl_xor(m[t], off, 64));

    // ---- pass B: denom + weighted feature sums ----
    float ws[NK], denoml[NK], acc[NK][8], accG[8], accS[8];
#pragma unroll
    for (int c = 0; c < 8; ++c) { accG[c] = 0.f; accS[c] = 0.f; }
#pragma unroll
    for (int t = 0; t < NK; ++t) {
        ws[t] = __expf(selfraw[t] - m[t]);
        denoml[t] = 0.f;
#pragma unroll
        for (int c = 0; c < 8; ++c) acc[t][c] = ws[t] * hs[c];
    }
    for (int base = beg; base < end; base += 8) {
        int e = base + ln;
        int col = 0;
        float dv = 0.f, wv[NK];
#pragma unroll
        for (int t = 0; t < NK; ++t) wv[t] = 0.f;
        if (e < end) {
            col = col_idx[e];
            dv = dinv[col];
            float4 sv = *(const float4*)(ssrcS + (size_t)col * 8 + soff);
            float svv[4] = {sv.x, sv.y, sv.z, sv.w};
#pragma unroll
            for (int t = 0; t < NK; ++t) {
                wv[t] = __expf(leaky(svv[t] + sd[t]) - m[t]);
                denoml[t] += wv[t];
            }
        }
        int jcnt = end - base;
        if (jcnt > 8) jcnt = 8;
        // 1-ahead pipelined broadcast loop
        int cs0 = __shfl(col, (sub << 3), 64);
        bf16x8 hx = *(const bf16x8*)(hb + (size_t)cs0 * 64 + ln * 8);
        for (int j = 0; j < jcnt; ++j) {
            bf16x8 hxn;
            if (j + 1 < jcnt) {
                int csn = __shfl(col, (sub << 3) | (j + 1), 64);
                hxn = *(const bf16x8*)(hb + (size_t)csn * 64 + ln * 8);
            }
            int srcl = (sub << 3) | j;
            float dvj = __shfl(dv, srcl, 64);
            float wj[NK];
#pragma unroll
            for (int t = 0; t < NK; ++t) wj[t] = __shfl(wv[t], srcl, 64);
#pragma unroll
            for (int c = 0; c < 8; ++c) {
                float f = (float)hx[c];
                accS[c] += f;
                accG[c] += dvj * f;
#pragma unroll
                for (int t = 0; t < NK; ++t) acc[t][c] += wj[t] * f;
            }
            hx = hxn;
        }
    }
    float denom[NK];
#pragma unroll
    for (int t = 0; t < NK; ++t) {
        float w = denoml[t];
#pragma unroll
        for (int off = 1; off < 8; off <<= 1) w += __shfl_xor(w, off, 64);
        denom[t] = w + ws[t];
    }

    if (doGS) {
        float dvn = dinv[node];
        float cin = 1.0f / cntf[node];
        bf16x8 og, os;
#pragma unroll
        for (int c = 0; c < 8; ++c) {
            os[c] = (__bf16)(accS[c] * cin);
            og[c] = (__bf16)(dvn * accG[c] + dvn * dvn * hs[c]);
        }
        *(bf16x8*)(aggS + (size_t)node * 64 + ln * 8) = os;
        *(bf16x8*)(aggG + (size_t)node * 64 + ln * 8) = og;
    }
#pragma unroll
    for (int t = 0; t < NK; ++t) {
        bf16x8 oa;
        float inv = 1.0f / denom[t];
#pragma unroll
        for (int c = 0; c < 8; ++c) oa[c] = (__bf16)(acc[t][c] * inv);
        *(bf16x8*)(A + (size_t)t * N_NODES * 64 + (size_t)node * 64 + ln * 8) = oa;
    }
}

// ---------------- MFMA group GEMM ------------------------------------------
struct GArgs {
    const __bf16* G;
    const __bf16* S;
    const __bf16* Hb;
    const __bf16* A0;
    const __bf16* Wt;
    const float* bc;
    float* tg[4];
    __bf16* shadow_ptr;
    long long slot;
    int nk;
    int initmask;   // bit t: run starting at t does init-write
    int shadow_t;   // flush index writing the bf16 shadow (-1 none)
    int kidx[8];
    int tsel[8];
};

__global__ __launch_bounds__(256) void gemm_group(GArgs a) {
    __shared__ __bf16 Wl[64 * 264];  // row stride 264 bf16
    int tid = threadIdx.x;
    int wave = tid >> 6, lane = tid & 63;
    int quad = lane >> 4, mr = lane & 15;
    int r0 = blockIdx.x * 128 + wave * 32;
    bf16x8 gf[2][2], sf[2][2], hf[2][2];
#pragma unroll
    for (int rt = 0; rt < 2; ++rt) {
        int r = r0 + rt * 16 + mr;
        if (r > N_NODES - 1) r = N_NODES - 1;
#pragma unroll
        for (int hh = 0; hh < 2; ++hh) {
            int colj = hh * 32 + (quad << 3);
            gf[rt][hh] = *(const bf16x8*)(a.G + (size_t)r * 64 + colj);
            sf[rt][hh] = *(const bf16x8*)(a.S + (size_t)r * 64 + colj);
            hf[rt][hh] = *(const bf16x8*)(a.Hb + (size_t)r * 64 + colj);
        }
    }
    floatx4 acc[2][4];
    float bsum[4];
#pragma unroll
    for (int rt = 0; rt < 2; ++rt)
#pragma unroll
        for (int ct = 0; ct < 4; ++ct) acc[rt][ct] = (floatx4){0.f, 0.f, 0.f, 0.f};
#pragma unroll
    for (int ct = 0; ct < 4; ++ct) bsum[ct] = 0.f;
    int runstart = 0;
    for (int t = 0; t < a.nk; ++t) {
        int k = a.kidx[t];
        __syncthreads();
        {
            const uint4* src = (const uint4*)(a.Wt + (size_t)k * 16384);
            for (int i = tid; i < 2048; i += 256) {
                int row = i >> 5, colj = (i & 31) << 3;
                *(uint4*)&Wl[row * 264 + colj] = src[i];
            }
        }
        __syncthreads();
        const __bf16* Ap = a.A0 + (size_t)t * a.slot;
        bf16x8 af[2][2];
#pragma unroll
        for (int rt = 0; rt < 2; ++rt) {
            int r = r0 + rt * 16 + mr;
            if (r > N_NODES - 1) r = N_NODES - 1;
#pragma unroll
            for (int hh = 0; hh < 2; ++hh)
                af[rt][hh] = *(const bf16x8*)(Ap + (size_t)r * 64 + hh * 32 + (quad << 3));
        }
        const float* bp = a.bc + k * 64;
#pragma unroll
        for (int ct = 0; ct < 4; ++ct) bsum[ct] += bp[ct * 16 + mr];
#pragma unroll
        for (int seg = 0; seg < 4; ++seg) {
#pragma unroll
            for (int hh = 0; hh < 2; ++hh) {
                int kt = seg * 2 + hh;
                bf16x8 a0 = (seg == 0) ? gf[0][hh] : (seg == 1) ? sf[0][hh]
                            : (seg == 2) ? hf[0][hh] : af[0][hh];
                bf16x8 a1 = (seg == 0) ? gf[1][hh] : (seg == 1) ? sf[1][hh]
                            : (seg == 2) ? hf[1][hh] : af[1][hh];
#pragma unroll
                for (int ct = 0; ct < 4; ++ct) {
                    bf16x8 bfr = *(const bf16x8*)&Wl[(ct * 16 + mr) * 264 + (kt << 5) + (quad << 3)];
                    acc[0][ct] = __builtin_amdgcn_mfma_f32_16x16x32_bf16(a0, bfr, acc[0][ct], 0, 0, 0);
                    acc[1][ct] = __builtin_amdgcn_mfma_f32_16x16x32_bf16(a1, bfr, acc[1][ct], 0, 0, 0);
                }
            }
        }
        bool flush = (t == a.nk - 1) || (a.tsel[t + 1] != a.tsel[t]);
        if (flush) {
            float* tgt = a.tg[a.tsel[t]];
            int init = (a.initmask >> runstart) & 1;
            bool shadow = (t == a.shadow_t);
            __bf16* sh = a.shadow_ptr;
#pragma unroll
            for (int rt = 0; rt < 2; ++rt) {
#pragma unroll
                for (int reg = 0; reg < 4; ++reg) {
                    int r = r0 + rt * 16 + quad * 4 + reg;
                    if (r < N_NODES) {
#pragma unroll
                        for (int ct = 0; ct < 4; ++ct) {
                            int c = ct * 16 + mr;
                            float v = acc[rt][ct][reg] + bsum[ct];
                            size_t idx = (size_t)r * 64 + c;
                            float nv = init ? v : (tgt[idx] + v);
                            tgt[idx] = nv;
                            if (shadow) sh[idx] = (__bf16)nv;
                        }
                    }
                }
            }
#pragma unroll
            for (int rt = 0; rt < 2; ++rt)
#pragma unroll
                for (int ct = 0; ct < 4; ++ct) acc[rt][ct] = (floatx4){0.f, 0.f, 0.f, 0.f};
#pragma unroll
            for (int ct = 0; ct < 4; ++ct) bsum[ct] = 0.f;
            runstart = t + 1;
        }
    }
}

extern "C" void kernel_launch(void* const* d_in, const int* in_sizes, int n_in,
                              void* d_out, int out_size, void* d_ws, size_t ws_size,
                              hipStream_t stream) {
    const float* x       = (const float*)d_in[0];
    const int*   ei      = (const int*)d_in[1];
    const float* alphas  = (const float*)d_in[2];
    const float* gcn_W   = (const float*)d_in[3];
    const float* gcn_b   = (const float*)d_in[4];
    const float* sage_Wl = (const float*)d_in[5];
    const float* sage_Wr = (const float*)d_in[6];
    const float* sage_b  = (const float*)d_in[7];
    const float* gat_W   = (const float*)d_in[8];
    const float* a_src   = (const float*)d_in[9];
    const float* a_dst   = (const float*)d_in[10];
    const float* gat_b   = (const float*)d_in[11];
    float* out = (float*)d_out;

    char* p = (char*)d_ws;
    auto alloc = [&](size_t bytes) -> char* {
        char* r = p;
        p += (bytes + 255) & ~(size_t)255;
        return r;
    };
    const size_t NCf = (size_t)N_NODES * CCH;
    const size_t NC32 = NCf * 4;
    const size_t NC16 = NCf * 2;
    float* sb[3];
    sb[0] = (float*)alloc(NC32);
    sb[1] = (float*)alloc(NC32);
    sb[2] = (float*)alloc(NC32);
    __bf16* hbuf[4];  // bf16 shadows of x, sb0, sb1, sb2
    for (int i = 0; i < 4; ++i) hbuf[i] = (__bf16*)alloc(NC16);
    __bf16* aggG = (__bf16*)alloc(NC16);
    __bf16* aggS = (__bf16*)alloc(NC16);
    float* ssrcS = (float*)alloc((size_t)N_NODES * 8 * 4);
    float* sdstS = (float*)alloc((size_t)N_NODES * 8 * 4);
    float* dinv  = (float*)alloc(N_NODES * 4);
    float* cntf  = (float*)alloc(N_NODES * 4);
    int* row_ptr = (int*)alloc((N_NODES + 1) * 4);
    int* col_idx = (int*)alloc((size_t)N_EDGES * 4);
    int* indeg   = (int*)alloc(N_NODES * 4);
    int* bsum    = (int*)alloc(NBLK * 4);
    __bf16* Wt   = (__bf16*)alloc((size_t)N_MIX * 16384 * 2);
    float* bcv   = (float*)alloc(N_MIX * 64 * 4);
    float* vs    = (float*)alloc(N_MIX * 64 * 4);
    float* vd    = (float*)alloc(N_MIX * 64 * 4);

    size_t used = (size_t)(p - (char*)d_ws);
    int navail = (int)((ws_size > used) ? ((ws_size - used) / NC16) : 0);
    if (navail < 1) navail = 1;
    if (navail > 4) navail = 4;
    __bf16* Abuf = (__bf16*)alloc((size_t)navail * NC16);

    hipMemsetAsync(indeg, 0, N_NODES * 4, stream);

    prep_weights<<<N_MIX, 256, 0, stream>>>(alphas, gcn_W, gcn_b, sage_Wl, sage_Wr, sage_b,
                                            gat_W, a_src, a_dst, gat_b, Wt, bcv, vs, vd);
    convert_bf16<<<(int)((NCf / 4 + 255) / 256), 256, 0, stream>>>((const float4*)x, hbuf[0],
                                                                   (int)(NCf / 4));
    count_indeg<<<(N_EDGES + 255) / 256, 256, 0, stream>>>(ei, indeg);
    deg_block_reduce<<<NBLK, 256, 0, stream>>>(indeg, bsum);
    scan_bsum<<<1, 256, 0, stream>>>(bsum, row_ptr);
    scan_write<<<NBLK, 256, 0, stream>>>(indeg, bsum, row_ptr, dinv, cntf);
    fill_csr<<<(N_EDGES + 255) / 256, 256, 0, stream>>>(ei, row_ptr, indeg, col_idx);

    const int SCORE_GRID = (N_NODES + 3) / 4;     // 12500
    const int AGG_GRID = N_NODES / 16;            // 3125 blocks x 128 thr (16 nodes/blk)
    const int GEMM_GRID = (N_NODES + 127) / 128;  // 391

    float* targ[4] = {sb[0], sb[1], sb[2], out};
    struct Phase { int nk; int ks[8]; int tg[8]; };
    const Phase ph[4] = {
        {8, {0, 1, 2, 3, 5, 6, 9, 10}, {0, 0, 1, 1, 2, 2, 3, 3}},
        {3, {4, 7, 11, 0, 0, 0, 0, 0}, {1, 2, 3, 0, 0, 0, 0, 0}},
        {2, {8, 12, 0, 0, 0, 0, 0, 0}, {2, 3, 0, 0, 0, 0, 0, 0}},
        {1, {13, 0, 0, 0, 0, 0, 0, 0}, {3, 0, 0, 0, 0, 0, 0, 0}},
    };

    for (int st = 0; st < 4; ++st) {
        const Phase& P = ph[st];
        const float* h = (st == 0) ? x : sb[st - 1];
        const __bf16* hb = hbuf[st];
        unsigned kmapAll = 0;
        for (int t = 0; t < P.nk; ++t) kmapAll |= (unsigned)P.ks[t] << (4 * t);
        switch (P.nk) {
            case 8: score_kernel<8><<<SCORE_GRID, 256, 0, stream>>>(h, vs, vd, kmapAll, ssrcS, sdstS); break;
            case 3: score_kernel<3><<<SCORE_GRID, 256, 0, stream>>>(h, vs, vd, kmapAll, ssrcS, sdstS); break;
            case 2: score_kernel<2><<<SCORE_GRID, 256, 0, stream>>>(h, vs, vd, kmapAll, ssrcS, sdstS); break;
            default: score_kernel<1><<<SCORE_GRID, 256, 0, stream>>>(h, vs, vd, kmapAll, ssrcS, sdstS); break;
        }
        int gs = (navail < 4) ? navail : 4;
        for (int done = 0; done < P.nk;) {
            int g = gs;
            if (g > P.nk - done) g = P.nk - done;
            int doGS = (done == 0) ? 1 : 0;
            switch (g) {
                case 4: fused_gather<4><<<AGG_GRID, 128, 0, stream>>>(hb, row_ptr, col_idx, dinv, cntf, ssrcS, sdstS, done, doGS, aggG, aggS, Abuf); break;
                case 3: fused_gather<3><<<AGG_GRID, 128, 0, stream>>>(hb, row_ptr, col_idx, dinv, cntf, ssrcS, sdstS, done, doGS, aggG, aggS, Abuf); break;
                case 2: fused_gather<2><<<AGG_GRID, 128, 0, stream>>>(hb, row_ptr, col_idx, dinv, cntf, ssrcS, sdstS, done, doGS, aggG, aggS, Abuf); break;
                default: fused_gather<1><<<AGG_GRID, 128, 0, stream>>>(hb, row_ptr, col_idx, dinv, cntf, ssrcS, sdstS, done, doGS, aggG, aggS, Abuf); break;
            }
            GArgs ga;
            ga.G = aggG; ga.S = aggS; ga.Hb = hb; ga.A0 = Abuf;
            ga.Wt = Wt; ga.bc = bcv;
            for (int i = 0; i < 4; ++i) ga.tg[i] = targ[i];
            ga.slot = (long long)NCf;
            ga.nk = g;
            ga.initmask = 0;
            ga.shadow_t = -1;
            ga.shadow_ptr = hbuf[0];  // dummy default
            for (int j = 0; j < g; ++j) {
                int k = P.ks[done + j];
                ga.kidx[j] = k;
                ga.tsel[j] = P.tg[done + j];
                if (k == 0 || k == 2 || k == 5 || k == 9) ga.initmask |= (1 << j);
                if (k == 1) { ga.shadow_t = j; ga.shadow_ptr = hbuf[1]; }
                if (k == 4) { ga.shadow_t = j; ga.shadow_ptr = hbuf[2]; }
                if (k == 8) { ga.shadow_t = j; ga.shadow_ptr = hbuf[3]; }
            }
            for (int j = g; j < 8; ++j) { ga.kidx[j] = 0; ga.tsel[j] = (j > 0) ? ga.tsel[j - 1] : 0; }
            gemm_group<<<GEMM_GRID, 256, 0, stream>>>(ga);
            done += g;
        }
    }
}

// Round 8
// 544.827 us; speedup vs baseline: 1.1407x; 1.1407x over previous
//
#include <hip/hip_runtime.h>

#define N_NODES 50000
#define N_EDGES 800000
#define CCH 64
#define N_MIX 14

typedef __bf16 bf16x8 __attribute__((ext_vector_type(8)));
typedef __bf16 bf16x4 __attribute__((ext_vector_type(4)));
typedef float floatx4 __attribute__((ext_vector_type(4)));

__device__ __forceinline__ float leaky(float x) {
    return fmaxf(x, 0.2f * x);
}

// ---------------- weight prep --------------------------------------------
// Wt[k] : 64(out-col) x 256(in-dim) bf16, transposed, scale-folded.
//   j<64: g*w0*gcn_W ; j<128: g*w1*sage_Wl ;
//   j<192: g*w1*sage_Wr + I*(g*w3 + (k>=11 ? 0.25 : 0)) ; j<256: g*w2*gat_W
// g=0.25 for k>=9 (final mean folded); +0.25*I for k in {11,12,13} folds
// final_mean's 0.25*(s2+s3+s4) since those k's H-input IS s2/s3/s4.
__global__ void prep_weights(const float* __restrict__ alphas,
                             const float* __restrict__ gcn_W, const float* __restrict__ gcn_b,
                             const float* __restrict__ sage_Wl, const float* __restrict__ sage_Wr,
                             const float* __restrict__ sage_b, const float* __restrict__ gat_Wp,
                             const float* __restrict__ a_src, const float* __restrict__ a_dst,
                             const float* __restrict__ gat_b,
                             __bf16* __restrict__ Wt, float* __restrict__ bc,
                             float* __restrict__ vs, float* __restrict__ vd) {
    int k = blockIdx.x;
    __shared__ float w[5];
    if (threadIdx.x == 0) {
        float a[5], m = -1e30f, s = 0.f;
        for (int i = 0; i < 5; ++i) { a[i] = alphas[k * 5 + i]; m = fmaxf(m, a[i]); }
        for (int i = 0; i < 5; ++i) { a[i] = __expf(a[i] - m); s += a[i]; }
        for (int i = 0; i < 5; ++i) w[i] = a[i] / s;
    }
    __syncthreads();
    float gamma = (k >= 9) ? 0.25f : 1.0f;
    float w0 = gamma * w[0], w1 = gamma * w[1], w2 = gamma * w[2], w3 = gamma * w[3];
    float idext = (k >= 11) ? 0.25f : 0.f;
    for (int idx = threadIdx.x; idx < 64 * 256; idx += blockDim.x) {
        int c = idx >> 8, j = idx & 255;
        float v;
        if (j < 64)       v = w0 * gcn_W[k * 4096 + j * 64 + c];
        else if (j < 128) v = w1 * sage_Wl[k * 4096 + (j - 64) * 64 + c];
        else if (j < 192) {
            int jj = j - 128;
            v = w1 * sage_Wr[k * 4096 + jj * 64 + c];
            if (jj == c) v += w3 + idext;
        } else {
            v = w2 * gat_Wp[k * 4096 + (j - 192) * 64 + c];
        }
        Wt[(size_t)k * 16384 + idx] = (__bf16)v;
    }
    if (threadIdx.x < 64) {
        int r = threadIdx.x;
        bc[k * 64 + r] = gamma * (w[0] * gcn_b[k * 64 + r] + w[1] * sage_b[k * 64 + r] +
                                  w[2] * gat_b[k * 64 + r]);
        float s1 = 0.f, s2 = 0.f;
        for (int j = 0; j < 64; ++j) {
            float wv_ = gat_Wp[k * 4096 + r * 64 + j];
            s1 += wv_ * a_src[k * 64 + j];
            s2 += wv_ * a_dst[k * 64 + j];
        }
        vs[k * 64 + r] = s1;
        vd[k * 64 + r] = s2;
    }
}

// Per-phase score V matrix: Vph[p] is 16x64 bf16. n<8: vs of phase-k slot n;
// n>=8: vd of slot n-8; zero for slots >= nk.
__global__ void prep_scoreV(const float* __restrict__ vs, const float* __restrict__ vd,
                            __bf16* __restrict__ Vph,
                            unsigned km0, unsigned km1, unsigned km2, unsigned km3,
                            unsigned nks) {
    int p = blockIdx.x;
    unsigned km = (p == 0) ? km0 : (p == 1) ? km1 : (p == 2) ? km2 : km3;
    int nk = (nks >> (p * 4)) & 15;
    for (int idx = threadIdx.x; idx < 1024; idx += blockDim.x) {
        int n = idx >> 6, kk = idx & 63;
        int t = n & 7;
        float v = 0.f;
        if (t < nk) {
            int k = (km >> (4 * t)) & 15;
            v = (n < 8) ? vs[k * 64 + kk] : vd[k * 64 + kk];
        }
        Vph[p * 1024 + n * 64 + kk] = (__bf16)v;
    }
}

__global__ void convert_bf16(const float4* __restrict__ src, __bf16* __restrict__ dst, int n4) {
    int i = blockIdx.x * blockDim.x + threadIdx.x;
    if (i < n4) {
        float4 v = src[i];
        dst[i * 4 + 0] = (__bf16)v.x;
        dst[i * 4 + 1] = (__bf16)v.y;
        dst[i * 4 + 2] = (__bf16)v.z;
        dst[i * 4 + 3] = (__bf16)v.w;
    }
}

// ---------------- CSR build ------------------------------------------------
__global__ void count_indeg(const int* __restrict__ ei, int* __restrict__ indeg) {
    int e = blockIdx.x * blockDim.x + threadIdx.x;
    if (e < N_EDGES) atomicAdd(&indeg[ei[N_EDGES + e]], 1);
}

#define NBLK 196  // ceil(50000/256)

__global__ __launch_bounds__(256) void deg_block_reduce(const int* __restrict__ indeg,
                                                        int* __restrict__ bsum) {
    int i = blockIdx.x * 256 + threadIdx.x;
    int v = (i < N_NODES) ? indeg[i] : 0;
#pragma unroll
    for (int off = 1; off < 64; off <<= 1) v += __shfl_xor(v, off, 64);
    __shared__ int ws_[4];
    if ((threadIdx.x & 63) == 0) ws_[threadIdx.x >> 6] = v;
    __syncthreads();
    if (threadIdx.x == 0) bsum[blockIdx.x] = ws_[0] + ws_[1] + ws_[2] + ws_[3];
}

__global__ __launch_bounds__(256) void scan_bsum(int* __restrict__ bsum, int* __restrict__ row_ptr) {
    __shared__ int s[256];
    int t = threadIdx.x;
    int v = (t < NBLK) ? bsum[t] : 0;
    s[t] = v;
    __syncthreads();
    for (int off = 1; off < 256; off <<= 1) {
        int tmp = (t >= off) ? s[t - off] : 0;
        __syncthreads();
        s[t] += tmp;
        __syncthreads();
    }
    if (t < NBLK) bsum[t] = s[t] - v;  // exclusive
    if (t == 0) row_ptr[N_NODES] = s[255];
}

__global__ __launch_bounds__(256) void scan_write(int* __restrict__ indeg,
                                                  const int* __restrict__ bsum,
                                                  int* __restrict__ row_ptr,
                                                  float* __restrict__ dinv,
                                                  float* __restrict__ cntf) {
    int i = blockIdx.x * 256 + threadIdx.x;
    int lane = threadIdx.x & 63, wv = threadIdx.x >> 6;
    int val = (i < N_NODES) ? indeg[i] : 0;
    int inc = val;
#pragma unroll
    for (int off = 1; off < 64; off <<= 1) {
        int t2 = __shfl_up(inc, off, 64);
        if (lane >= off) inc += t2;
    }
    __shared__ int wsum[4];
    if (lane == 63) wsum[wv] = inc;
    __syncthreads();
    int woff = 0;
    for (int j = 0; j < wv; ++j) woff += wsum[j];
    if (i < N_NODES) {
        row_ptr[i] = bsum[blockIdx.x] + woff + inc - val;
        dinv[i] = rsqrtf((float)(val + 1));
        cntf[i] = (float)(val > 0 ? val : 1);
        indeg[i] = 0;  // reuse as fill counter
    }
}

__global__ void fill_csr(const int* __restrict__ ei, const int* __restrict__ row_ptr,
                         int* __restrict__ fill_cnt, int* __restrict__ col_idx) {
    int e = blockIdx.x * blockDim.x + threadIdx.x;
    if (e < N_EDGES) {
        int d = ei[N_EDGES + e];
        int pos = row_ptr[d] + atomicAdd(&fill_cnt[d], 1);
        col_idx[pos] = ei[e];
    }
}

// ---------------- MFMA score kernel ----------------------------------------
// scores(50000x16) = hb(50000x64) @ V^T. V is 16x64 (n,k). One wave = 32 rows
// (2 row-tiles). Epilogue scatters to stride-8 ssrcS/sdstS.
__global__ __launch_bounds__(256) void score_mfma(const __bf16* __restrict__ hb,
                                                  const __bf16* __restrict__ V,
                                                  float* __restrict__ ssrcS,
                                                  float* __restrict__ sdstS) {
    int tid = threadIdx.x;
    int wave = tid >> 6, lane = tid & 63;
    int quad = lane >> 4, mr = lane & 15;
    int r0 = blockIdx.x * 128 + wave * 32;
    bf16x8 b0 = *(const bf16x8*)(V + mr * 64 + (quad << 3));
    bf16x8 b1 = *(const bf16x8*)(V + mr * 64 + 32 + (quad << 3));
#pragma unroll
    for (int rt = 0; rt < 2; ++rt) {
        int r = r0 + rt * 16 + mr;
        if (r > N_NODES - 1) r = N_NODES - 1;
        bf16x8 a0 = *(const bf16x8*)(hb + (size_t)r * 64 + (quad << 3));
        bf16x8 a1 = *(const bf16x8*)(hb + (size_t)r * 64 + 32 + (quad << 3));
        floatx4 acc = (floatx4){0.f, 0.f, 0.f, 0.f};
        acc = __builtin_amdgcn_mfma_f32_16x16x32_bf16(a0, b0, acc, 0, 0, 0);
        acc = __builtin_amdgcn_mfma_f32_16x16x32_bf16(a1, b1, acc, 0, 0, 0);
#pragma unroll
        for (int reg = 0; reg < 4; ++reg) {
            int row = r0 + rt * 16 + quad * 4 + reg;
            if (row < N_NODES) {
                if (mr < 8) ssrcS[(size_t)row * 8 + mr] = acc[reg];
                else        sdstS[(size_t)row * 8 + (mr - 8)] = acc[reg];
            }
        }
    }
}

// ---------------- fused per-state gather: 8 nodes per wave -----------------
// sub = lane>>3 (node in wave), ln = lane&7. Each 8-lane group owns one node;
// lane ln covers channels 8*ln..8*ln+7 (bf16x8 = 16 B -> group covers the
// full 128-B row; a wave's load fetches 8 rows = 1 KB). Loop bounds are
// per-group (uniform within the 8 lanes). Scores at stride 8 -> float4 loads.
// NK <= 4 keeps acc[NK][8] register pressure under the 128-VGPR cliff.
template <int NK>
__global__ __launch_bounds__(128, 4) void fused_gather(
    const __bf16* __restrict__ hb, const int* __restrict__ row_ptr,
    const int* __restrict__ col_idx, const float* __restrict__ dinv,
    const float* __restrict__ cntf, const float* __restrict__ ssrcS,
    const float* __restrict__ sdstS, int soff, int doGS,
    __bf16* __restrict__ aggG, __bf16* __restrict__ aggS, __bf16* __restrict__ A) {
    int wid = blockIdx.x * 2 + (threadIdx.x >> 6);
    int lane = threadIdx.x & 63;
    int sub = lane >> 3, ln = lane & 7;
    int node = wid * 8 + sub;  // grid exact: 3125 blocks * 16 nodes
    int beg = row_ptr[node], end = row_ptr[node + 1];

    float sd[NK], selfraw[NK];
    {
        float4 sv = *(const float4*)(ssrcS + (size_t)node * 8 + soff);
        float4 dvv = *(const float4*)(sdstS + (size_t)node * 8 + soff);
        float svv[4] = {sv.x, sv.y, sv.z, sv.w};
        float dvl[4] = {dvv.x, dvv.y, dvv.z, dvv.w};
#pragma unroll
        for (int t = 0; t < NK; ++t) {
            sd[t] = dvl[t];
            selfraw[t] = leaky(svv[t] + sd[t]);
        }
    }
    bf16x8 hsb = *(const bf16x8*)(hb + (size_t)node * 64 + ln * 8);
    float hs[8];
#pragma unroll
    for (int c = 0; c < 8; ++c) hs[c] = (float)hsb[c];

    // ---- pass A: per-k max over in-edges ----
    float m[NK];
#pragma unroll
    for (int t = 0; t < NK; ++t) m[t] = selfraw[t];
    for (int base = beg; base < end; base += 8) {
        int e = base + ln;
        if (e < end) {
            int c2 = col_idx[e];
            float4 sv = *(const float4*)(ssrcS + (size_t)c2 * 8 + soff);
            float svv[4] = {sv.x, sv.y, sv.z, sv.w};
#pragma unroll
            for (int t = 0; t < NK; ++t) m[t] = fmaxf(m[t], leaky(svv[t] + sd[t]));
        }
    }
#pragma unroll
    for (int t = 0; t < NK; ++t)
#pragma unroll
        for (int off = 1; off < 8; off <<= 1) m[t] = fmaxf(m[t], __shfl_xor(m[t], off, 64));

    // ---- pass B: denom + weighted feature sums ----
    float ws[NK], denoml[NK], acc[NK][8], accG[8], accS[8];
#pragma unroll
    for (int c = 0; c < 8; ++c) { accG[c] = 0.f; accS[c] = 0.f; }
#pragma unroll
    for (int t = 0; t < NK; ++t) {
        ws[t] = __expf(selfraw[t] - m[t]);
        denoml[t] = 0.f;
#pragma unroll
        for (int c = 0; c < 8; ++c) acc[t][c] = ws[t] * hs[c];
    }
    for (int base = beg; base < end; base += 8) {
        int e = base + ln;
        int col = 0;
        float dv = 0.f, wv[NK];
#pragma unroll
        for (int t = 0; t < NK; ++t) wv[t] = 0.f;
        if (e < end) {
            col = col_idx[e];
            dv = dinv[col];
            float4 sv = *(const float4*)(ssrcS + (size_t)col * 8 + soff);
            float svv[4] = {sv.x, sv.y, sv.z, sv.w};
#pragma unroll
            for (int t = 0; t < NK; ++t) {
                wv[t] = __expf(leaky(svv[t] + sd[t]) - m[t]);
                denoml[t] += wv[t];
            }
        }
        int jcnt = end - base;
        if (jcnt > 8) jcnt = 8;
        // 1-ahead pipelined broadcast loop
        int cs0 = __shfl(col, (sub << 3), 64);
        bf16x8 hx = *(const bf16x8*)(hb + (size_t)cs0 * 64 + ln * 8);
        for (int j = 0; j < jcnt; ++j) {
            bf16x8 hxn;
            if (j + 1 < jcnt) {
                int csn = __shfl(col, (sub << 3) | (j + 1), 64);
                hxn = *(const bf16x8*)(hb + (size_t)csn * 64 + ln * 8);
            }
            int srcl = (sub << 3) | j;
            float dvj = __shfl(dv, srcl, 64);
            float wj[NK];
#pragma unroll
            for (int t = 0; t < NK; ++t) wj[t] = __shfl(wv[t], srcl, 64);
#pragma unroll
            for (int c = 0; c < 8; ++c) {
                float f = (float)hx[c];
                accS[c] += f;
                accG[c] += dvj * f;
#pragma unroll
                for (int t = 0; t < NK; ++t) acc[t][c] += wj[t] * f;
            }
            hx = hxn;
        }
    }
    float denom[NK];
#pragma unroll
    for (int t = 0; t < NK; ++t) {
        float w = denoml[t];
#pragma unroll
        for (int off = 1; off < 8; off <<= 1) w += __shfl_xor(w, off, 64);
        denom[t] = w + ws[t];
    }

    if (doGS) {
        float dvn = dinv[node];
        float cin = 1.0f / cntf[node];
        bf16x8 og, os;
#pragma unroll
        for (int c = 0; c < 8; ++c) {
            os[c] = (__bf16)(accS[c] * cin);
            og[c] = (__bf16)(dvn * accG[c] + dvn * dvn * hs[c]);
        }
        *(bf16x8*)(aggS + (size_t)node * 64 + ln * 8) = os;
        *(bf16x8*)(aggG + (size_t)node * 64 + ln * 8) = og;
    }
#pragma unroll
    for (int t = 0; t < NK; ++t) {
        bf16x8 oa;
        float inv = 1.0f / denom[t];
#pragma unroll
        for (int c = 0; c < 8; ++c) oa[c] = (__bf16)(acc[t][c] * inv);
        *(bf16x8*)(A + (size_t)t * N_NODES * 64 + (size_t)node * 64 + ln * 8) = oa;
    }
}

// ---------------- MFMA group GEMM ------------------------------------------
struct GArgs {
    const __bf16* G;
    const __bf16* S;
    const __bf16* Hb;
    const __bf16* A0;
    const __bf16* Wt;
    const float* bc;
    float* tg[4];
    __bf16* shadow_ptr;
    long long slot;
    int nk;
    int initmask;   // bit t: run starting at t does init-write
    int shadow_t;   // flush index writing the bf16 shadow (-1 none)
    int kidx[8];
    int tsel[8];
};

__global__ __launch_bounds__(256) void gemm_group(GArgs a) {
    __shared__ __bf16 Wl[64 * 264];  // row stride 264 bf16
    int tid = threadIdx.x;
    int wave = tid >> 6, lane = tid & 63;
    int quad = lane >> 4, mr = lane & 15;
    int r0 = blockIdx.x * 128 + wave * 32;
    bf16x8 gf[2][2], sf[2][2], hf[2][2];
#pragma unroll
    for (int rt = 0; rt < 2; ++rt) {
        int r = r0 + rt * 16 + mr;
        if (r > N_NODES - 1) r = N_NODES - 1;
#pragma unroll
        for (int hh = 0; hh < 2; ++hh) {
            int colj = hh * 32 + (quad << 3);
            gf[rt][hh] = *(const bf16x8*)(a.G + (size_t)r * 64 + colj);
            sf[rt][hh] = *(const bf16x8*)(a.S + (size_t)r * 64 + colj);
            hf[rt][hh] = *(const bf16x8*)(a.Hb + (size_t)r * 64 + colj);
        }
    }
    floatx4 acc[2][4];
    float bsum[4];
#pragma unroll
    for (int rt = 0; rt < 2; ++rt)
#pragma unroll
        for (int ct = 0; ct < 4; ++ct) acc[rt][ct] = (floatx4){0.f, 0.f, 0.f, 0.f};
#pragma unroll
    for (int ct = 0; ct < 4; ++ct) bsum[ct] = 0.f;
    int runstart = 0;
    for (int t = 0; t < a.nk; ++t) {
        int k = a.kidx[t];
        __syncthreads();
        {
            const uint4* src = (const uint4*)(a.Wt + (size_t)k * 16384);
            for (int i = tid; i < 2048; i += 256) {
                int row = i >> 5, colj = (i & 31) << 3;
                *(uint4*)&Wl[row * 264 + colj] = src[i];
            }
        }
        __syncthreads();
        const __bf16* Ap = a.A0 + (size_t)t * a.slot;
        bf16x8 af[2][2];
#pragma unroll
        for (int rt = 0; rt < 2; ++rt) {
            int r = r0 + rt * 16 + mr;
            if (r > N_NODES - 1) r = N_NODES - 1;
#pragma unroll
            for (int hh = 0; hh < 2; ++hh)
                af[rt][hh] = *(const bf16x8*)(Ap + (size_t)r * 64 + hh * 32 + (quad << 3));
        }
        const float* bp = a.bc + k * 64;
#pragma unroll
        for (int ct = 0; ct < 4; ++ct) bsum[ct] += bp[ct * 16 + mr];
#pragma unroll
        for (int seg = 0; seg < 4; ++seg) {
#pragma unroll
            for (int hh = 0; hh < 2; ++hh) {
                int kt = seg * 2 + hh;
                bf16x8 a0 = (seg == 0) ? gf[0][hh] : (seg == 1) ? sf[0][hh]
                            : (seg == 2) ? hf[0][hh] : af[0][hh];
                bf16x8 a1 = (seg == 0) ? gf[1][hh] : (seg == 1) ? sf[1][hh]
                            : (seg == 2) ? hf[1][hh] : af[1][hh];
#pragma unroll
                for (int ct = 0; ct < 4; ++ct) {
                    bf16x8 bfr = *(const bf16x8*)&Wl[(ct * 16 + mr) * 264 + (kt << 5) + (quad << 3)];
                    acc[0][ct] = __builtin_amdgcn_mfma_f32_16x16x32_bf16(a0, bfr, acc[0][ct], 0, 0, 0);
                    acc[1][ct] = __builtin_amdgcn_mfma_f32_16x16x32_bf16(a1, bfr, acc[1][ct], 0, 0, 0);
                }
            }
        }
        bool flush = (t == a.nk - 1) || (a.tsel[t + 1] != a.tsel[t]);
        if (flush) {
            float* tgt = a.tg[a.tsel[t]];
            int init = (a.initmask >> runstart) & 1;
            bool shadow = (t == a.shadow_t);
            __bf16* sh = a.shadow_ptr;
#pragma unroll
            for (int rt = 0; rt < 2; ++rt) {
#pragma unroll
                for (int reg = 0; reg < 4; ++reg) {
                    int r = r0 + rt * 16 + quad * 4 + reg;
                    if (r < N_NODES) {
#pragma unroll
                        for (int ct = 0; ct < 4; ++ct) {
                            int c = ct * 16 + mr;
                            float v = acc[rt][ct][reg] + bsum[ct];
                            size_t idx = (size_t)r * 64 + c;
                            float nv = init ? v : (tgt[idx] + v);
                            tgt[idx] = nv;
                            if (shadow) sh[idx] = (__bf16)nv;
                        }
                    }
                }
            }
#pragma unroll
            for (int rt = 0; rt < 2; ++rt)
#pragma unroll
                for (int ct = 0; ct < 4; ++ct) acc[rt][ct] = (floatx4){0.f, 0.f, 0.f, 0.f};
#pragma unroll
            for (int ct = 0; ct < 4; ++ct) bsum[ct] = 0.f;
            runstart = t + 1;
        }
    }
}

extern "C" void kernel_launch(void* const* d_in, const int* in_sizes, int n_in,
                              void* d_out, int out_size, void* d_ws, size_t ws_size,
                              hipStream_t stream) {
    const float* x       = (const float*)d_in[0];
    const int*   ei      = (const int*)d_in[1];
    const float* alphas  = (const float*)d_in[2];
    const float* gcn_W   = (const float*)d_in[3];
    const float* gcn_b   = (const float*)d_in[4];
    const float* sage_Wl = (const float*)d_in[5];
    const float* sage_Wr = (const float*)d_in[6];
    const float* sage_b  = (const float*)d_in[7];
    const float* gat_W   = (const float*)d_in[8];
    const float* a_src   = (const float*)d_in[9];
    const float* a_dst   = (const float*)d_in[10];
    const float* gat_b   = (const float*)d_in[11];
    float* out = (float*)d_out;

    char* p = (char*)d_ws;
    auto alloc = [&](size_t bytes) -> char* {
        char* r = p;
        p += (bytes + 255) & ~(size_t)255;
        return r;
    };
    const size_t NCf = (size_t)N_NODES * CCH;
    const size_t NC32 = NCf * 4;
    const size_t NC16 = NCf * 2;
    float* sb[3];
    sb[0] = (float*)alloc(NC32);
    sb[1] = (float*)alloc(NC32);
    sb[2] = (float*)alloc(NC32);
    __bf16* hbuf[4];  // bf16 shadows of x, sb0, sb1, sb2
    for (int i = 0; i < 4; ++i) hbuf[i] = (__bf16*)alloc(NC16);
    __bf16* aggG = (__bf16*)alloc(NC16);
    __bf16* aggS = (__bf16*)alloc(NC16);
    float* ssrcS = (float*)alloc((size_t)N_NODES * 8 * 4);
    float* sdstS = (float*)alloc((size_t)N_NODES * 8 * 4);
    float* dinv  = (float*)alloc(N_NODES * 4);
    float* cntf  = (float*)alloc(N_NODES * 4);
    int* row_ptr = (int*)alloc((N_NODES + 1) * 4);
    int* col_idx = (int*)alloc((size_t)N_EDGES * 4);
    int* indeg   = (int*)alloc(N_NODES * 4);
    int* bsum    = (int*)alloc(NBLK * 4);
    __bf16* Wt   = (__bf16*)alloc((size_t)N_MIX * 16384 * 2);
    float* bcv   = (float*)alloc(N_MIX * 64 * 4);
    float* vs    = (float*)alloc(N_MIX * 64 * 4);
    float* vd    = (float*)alloc(N_MIX * 64 * 4);
    __bf16* Vph  = (__bf16*)alloc(4 * 1024 * 2);

    size_t used = (size_t)(p - (char*)d_ws);
    int navail = (int)((ws_size > used) ? ((ws_size - used) / NC16) : 0);
    if (navail < 1) navail = 1;
    if (navail > 4) navail = 4;
    __bf16* Abuf = (__bf16*)alloc((size_t)navail * NC16);

    hipMemsetAsync(indeg, 0, N_NODES * 4, stream);

    prep_weights<<<N_MIX, 256, 0, stream>>>(alphas, gcn_W, gcn_b, sage_Wl, sage_Wr, sage_b,
                                            gat_W, a_src, a_dst, gat_b, Wt, bcv, vs, vd);
    // phase k-sets: {0,1,2,3,5,6,9,10} / {4,7,11} / {8,12} / {13}
    prep_scoreV<<<4, 256, 0, stream>>>(vs, vd, Vph, 0xA9653210u, 0xB74u, 0xC8u, 0xDu, 0x1238u);
    convert_bf16<<<(int)((NCf / 4 + 255) / 256), 256, 0, stream>>>((const float4*)x, hbuf[0],
                                                                   (int)(NCf / 4));
    count_indeg<<<(N_EDGES + 255) / 256, 256, 0, stream>>>(ei, indeg);
    deg_block_reduce<<<NBLK, 256, 0, stream>>>(indeg, bsum);
    scan_bsum<<<1, 256, 0, stream>>>(bsum, row_ptr);
    scan_write<<<NBLK, 256, 0, stream>>>(indeg, bsum, row_ptr, dinv, cntf);
    fill_csr<<<(N_EDGES + 255) / 256, 256, 0, stream>>>(ei, row_ptr, indeg, col_idx);

    const int AGG_GRID = N_NODES / 16;            // 3125 blocks x 128 thr (16 nodes/blk)
    const int GEMM_GRID = (N_NODES + 127) / 128;  // 391

    float* targ[4] = {sb[0], sb[1], sb[2], out};
    struct Phase { int nk; int ks[8]; int tg[8]; };
    const Phase ph[4] = {
        {8, {0, 1, 2, 3, 5, 6, 9, 10}, {0, 0, 1, 1, 2, 2, 3, 3}},
        {3, {4, 7, 11, 0, 0, 0, 0, 0}, {1, 2, 3, 0, 0, 0, 0, 0}},
        {2, {8, 12, 0, 0, 0, 0, 0, 0}, {2, 3, 0, 0, 0, 0, 0, 0}},
        {1, {13, 0, 0, 0, 0, 0, 0, 0}, {3, 0, 0, 0, 0, 0, 0, 0}},
    };

    for (int st = 0; st < 4; ++st) {
        const Phase& P = ph[st];
        const __bf16* hb = hbuf[st];
        score_mfma<<<GEMM_GRID, 256, 0, stream>>>(hb, Vph + st * 1024, ssrcS, sdstS);
        int gs = (navail < 4) ? navail : 4;
        for (int done = 0; done < P.nk;) {
            int g = gs;
            if (g > P.nk - done) g = P.nk - done;
            int doGS = (done == 0) ? 1 : 0;
            switch (g) {
                case 4: fused_gather<4><<<AGG_GRID, 128, 0, stream>>>(hb, row_ptr, col_idx, dinv, cntf, ssrcS, sdstS, done, doGS, aggG, aggS, Abuf); break;
                case 3: fused_gather<3><<<AGG_GRID, 128, 0, stream>>>(hb, row_ptr, col_idx, dinv, cntf, ssrcS, sdstS, done, doGS, aggG, aggS, Abuf); break;
                case 2: fused_gather<2><<<AGG_GRID, 128, 0, stream>>>(hb, row_ptr, col_idx, dinv, cntf, ssrcS, sdstS, done, doGS, aggG, aggS, Abuf); break;
                default: fused_gather<1><<<AGG_GRID, 128, 0, stream>>>(hb, row_ptr, col_idx, dinv, cntf, ssrcS, sdstS, done, doGS, aggG, aggS, Abuf); break;
            }
            GArgs ga;
            ga.G = aggG; ga.S = aggS; ga.Hb = hb; ga.A0 = Abuf;
            ga.Wt = Wt; ga.bc = bcv;
            for (int i = 0; i < 4; ++i) ga.tg[i] = targ[i];
            ga.slot = (long long)NCf;
            ga.nk = g;
            ga.initmask = 0;
            ga.shadow_t = -1;
            ga.shadow_ptr = hbuf[0];  // dummy default
            for (int j = 0; j < g; ++j) {
                int k = P.ks[done + j];
                ga.kidx[j] = k;
                ga.tsel[j] = P.tg[done + j];
                if (k == 0 || k == 2 || k == 5 || k == 9) ga.initmask |= (1 << j);
                if (k == 1) { ga.shadow_t = j; ga.shadow_ptr = hbuf[1]; }
                if (k == 4) { ga.shadow_t = j; ga.shadow_ptr = hbuf[2]; }
                if (k == 8) { ga.shadow_t = j; ga.shadow_ptr = hbuf[3]; }
            }
            for (int j = g; j < 8; ++j) { ga.kidx[j] = 0; ga.tsel[j] = (j > 0) ? ga.tsel[j - 1] : 0; }
            gemm_group<<<GEMM_GRID, 256, 0, stream>>>(ga);
            done += g;
        }
    }
}

// Round 9
// 533.391 us; speedup vs baseline: 1.1651x; 1.0214x over previous
//
#include <hip/hip_runtime.h>

#define N_NODES 50000
#define N_EDGES 800000
#define CCH 64
#define N_MIX 14
#define NBUCK 196   // ceil(50000/256)
#define BCAP 6144   // per-bucket edge capacity (mean ~4082, sigma ~64)

typedef __bf16 bf16x8 __attribute__((ext_vector_type(8)));
typedef float floatx4 __attribute__((ext_vector_type(4)));

__device__ __forceinline__ float leaky(float x) {
    return fmaxf(x, 0.2f * x);
}

// ---------------- weight prep --------------------------------------------
// Wt[k] : 64(out-col) x 256(in-dim) bf16, transposed, scale-folded.
//   j<64: g*w0*gcn_W ; j<128: g*w1*sage_Wl ;
//   j<192: g*w1*sage_Wr + I*(g*w3 + (k>=11 ? 0.25 : 0)) ; j<256: g*w2*gat_W
// g=0.25 for k>=9 (final mean folded); +0.25*I for k in {11,12,13} folds
// final_mean's 0.25*(s2+s3+s4) since those k's H-input IS s2/s3/s4.
__global__ void prep_weights(const float* __restrict__ alphas,
                             const float* __restrict__ gcn_W, const float* __restrict__ gcn_b,
                             const float* __restrict__ sage_Wl, const float* __restrict__ sage_Wr,
                             const float* __restrict__ sage_b, const float* __restrict__ gat_Wp,
                             const float* __restrict__ a_src, const float* __restrict__ a_dst,
                             const float* __restrict__ gat_b,
                             __bf16* __restrict__ Wt, float* __restrict__ bc,
                             float* __restrict__ vs, float* __restrict__ vd) {
    int k = blockIdx.x;
    __shared__ float w[5];
    if (threadIdx.x == 0) {
        float a[5], m = -1e30f, s = 0.f;
        for (int i = 0; i < 5; ++i) { a[i] = alphas[k * 5 + i]; m = fmaxf(m, a[i]); }
        for (int i = 0; i < 5; ++i) { a[i] = __expf(a[i] - m); s += a[i]; }
        for (int i = 0; i < 5; ++i) w[i] = a[i] / s;
    }
    __syncthreads();
    float gamma = (k >= 9) ? 0.25f : 1.0f;
    float w0 = gamma * w[0], w1 = gamma * w[1], w2 = gamma * w[2], w3 = gamma * w[3];
    float idext = (k >= 11) ? 0.25f : 0.f;
    for (int idx = threadIdx.x; idx < 64 * 256; idx += blockDim.x) {
        int c = idx >> 8, j = idx & 255;
        float v;
        if (j < 64)       v = w0 * gcn_W[k * 4096 + j * 64 + c];
        else if (j < 128) v = w1 * sage_Wl[k * 4096 + (j - 64) * 64 + c];
        else if (j < 192) {
            int jj = j - 128;
            v = w1 * sage_Wr[k * 4096 + jj * 64 + c];
            if (jj == c) v += w3 + idext;
        } else {
            v = w2 * gat_Wp[k * 4096 + (j - 192) * 64 + c];
        }
        Wt[(size_t)k * 16384 + idx] = (__bf16)v;
    }
    if (threadIdx.x < 64) {
        int r = threadIdx.x;
        bc[k * 64 + r] = gamma * (w[0] * gcn_b[k * 64 + r] + w[1] * sage_b[k * 64 + r] +
                                  w[2] * gat_b[k * 64 + r]);
        float s1 = 0.f, s2 = 0.f;
        for (int j = 0; j < 64; ++j) {
            float wv_ = gat_Wp[k * 4096 + r * 64 + j];
            s1 += wv_ * a_src[k * 64 + j];
            s2 += wv_ * a_dst[k * 64 + j];
        }
        vs[k * 64 + r] = s1;
        vd[k * 64 + r] = s2;
    }
}

// Per-phase score V matrix: Vph[p] is 16x64 bf16. n<8: vs of phase-k slot n;
// n>=8: vd of slot n-8; zero for slots >= nk.
__global__ void prep_scoreV(const float* __restrict__ vs, const float* __restrict__ vd,
                            __bf16* __restrict__ Vph,
                            unsigned km0, unsigned km1, unsigned km2, unsigned km3,
                            unsigned nks) {
    int p = blockIdx.x;
    unsigned km = (p == 0) ? km0 : (p == 1) ? km1 : (p == 2) ? km2 : km3;
    int nk = (nks >> (p * 4)) & 15;
    for (int idx = threadIdx.x; idx < 1024; idx += blockDim.x) {
        int n = idx >> 6, kk = idx & 63;
        int t = n & 7;
        float v = 0.f;
        if (t < nk) {
            int k = (km >> (4 * t)) & 15;
            v = (n < 8) ? vs[k * 64 + kk] : vd[k * 64 + kk];
        }
        Vph[p * 1024 + n * 64 + kk] = (__bf16)v;
    }
}

__global__ void convert_bf16(const float4* __restrict__ src, __bf16* __restrict__ dst, int n4) {
    int i = blockIdx.x * blockDim.x + threadIdx.x;
    if (i < n4) {
        float4 v = src[i];
        dst[i * 4 + 0] = (__bf16)v.x;
        dst[i * 4 + 1] = (__bf16)v.y;
        dst[i * 4 + 2] = (__bf16)v.z;
        dst[i * 4 + 3] = (__bf16)v.w;
    }
}

// ---------------- CSR build via bucket counting sort -----------------------
// bucket b = dst >> 8 covers nodes [b*256, b*256+255].
__global__ __launch_bounds__(256) void bucket_count(const int* __restrict__ ei,
                                                    int* __restrict__ bcount) {
    __shared__ int h[NBUCK];
    for (int i = threadIdx.x; i < NBUCK; i += 256) h[i] = 0;
    __syncthreads();
    for (int e = blockIdx.x * 256 + threadIdx.x; e < N_EDGES; e += gridDim.x * 256)
        atomicAdd(&h[ei[N_EDGES + e] >> 8], 1);
    __syncthreads();
    for (int i = threadIdx.x; i < NBUCK; i += 256)
        if (h[i]) atomicAdd(&bcount[i], h[i]);
}

__global__ __launch_bounds__(256) void bucket_scan(const int* __restrict__ bcount,
                                                   int* __restrict__ bbase,
                                                   int* __restrict__ row_ptr) {
    __shared__ int s[256];
    int t = threadIdx.x;
    int v = (t < NBUCK) ? bcount[t] : 0;
    s[t] = v;
    __syncthreads();
    for (int o = 1; o < 256; o <<= 1) {
        int t2 = (t >= o) ? s[t - o] : 0;
        __syncthreads();
        s[t] += t2;
        __syncthreads();
    }
    if (t < NBUCK) bbase[t + 1] = s[t];
    if (t == 0) { bbase[0] = 0; row_ptr[N_NODES] = N_EDGES; }
}

// bfill padded: stride 16 ints (64 B) per bucket to avoid line contention.
__global__ __launch_bounds__(256) void bucket_scatter(const int* __restrict__ ei,
                                                      const int* __restrict__ bbase,
                                                      int* __restrict__ bfill,
                                                      unsigned long long* __restrict__ pairs) {
    int e = blockIdx.x * 256 + threadIdx.x;
    if (e < N_EDGES) {
        int s = ei[e], d = ei[N_EDGES + e];
        int b = d >> 8;
        int pos = atomicAdd(&bfill[b * 16], 1);
        pairs[(size_t)bbase[b] + pos] =
            (unsigned long long)(unsigned)s | ((unsigned long long)(unsigned)d << 32);
    }
}

__global__ __launch_bounds__(256) void bucket_sort(const unsigned long long* __restrict__ pairs,
                                                   const int* __restrict__ bbase,
                                                   int* __restrict__ row_ptr,
                                                   int* __restrict__ col_idx,
                                                   float* __restrict__ dinv,
                                                   float* __restrict__ cntf) {
    int b = blockIdx.x;
    __shared__ unsigned long long buf[BCAP];
    __shared__ int hist[256], off[256], cur[256];
    int tid = threadIdx.x;
    hist[tid] = 0;
    __syncthreads();
    int base = bbase[b], cnt = bbase[b + 1] - base;
    if (cnt > BCAP) cnt = BCAP;  // statistically impossible; hard safety
    for (int i = tid; i < cnt; i += 256) {
        unsigned long long pr = pairs[(size_t)base + i];
        buf[i] = pr;
        atomicAdd(&hist[(int)(pr >> 32) & 255], 1);
    }
    __syncthreads();
    int v = hist[tid];
    off[tid] = v;
    __syncthreads();
    for (int o = 1; o < 256; o <<= 1) {
        int t2 = (tid >= o) ? off[tid - o] : 0;
        __syncthreads();
        off[tid] += t2;
        __syncthreads();
    }
    int excl = off[tid] - v;
    int node = b * 256 + tid;
    if (node < N_NODES) {
        row_ptr[node] = base + excl;
        dinv[node] = rsqrtf((float)(v + 1));
        cntf[node] = (float)(v > 0 ? v : 1);
    }
    cur[tid] = excl;
    __syncthreads();
    for (int i = tid; i < cnt; i += 256) {
        unsigned long long pr = buf[i];
        int ln = (int)(pr >> 32) & 255;
        int pos = atomicAdd(&cur[ln], 1);
        col_idx[base + pos] = (int)(pr & 0xffffffffu);
    }
}

// ---------------- MFMA score kernel ----------------------------------------
// scores(50000x16) = hb(50000x64) @ V^T. V is 16x64 (n,k). One wave = 32 rows.
__global__ __launch_bounds__(256) void score_mfma(const __bf16* __restrict__ hb,
                                                  const __bf16* __restrict__ V,
                                                  float* __restrict__ ssrcS,
                                                  float* __restrict__ sdstS) {
    int tid = threadIdx.x;
    int wave = tid >> 6, lane = tid & 63;
    int quad = lane >> 4, mr = lane & 15;
    int r0 = blockIdx.x * 128 + wave * 32;
    bf16x8 b0 = *(const bf16x8*)(V + mr * 64 + (quad << 3));
    bf16x8 b1 = *(const bf16x8*)(V + mr * 64 + 32 + (quad << 3));
#pragma unroll
    for (int rt = 0; rt < 2; ++rt) {
        int r = r0 + rt * 16 + mr;
        if (r > N_NODES - 1) r = N_NODES - 1;
        bf16x8 a0 = *(const bf16x8*)(hb + (size_t)r * 64 + (quad << 3));
        bf16x8 a1 = *(const bf16x8*)(hb + (size_t)r * 64 + 32 + (quad << 3));
        floatx4 acc = (floatx4){0.f, 0.f, 0.f, 0.f};
        acc = __builtin_amdgcn_mfma_f32_16x16x32_bf16(a0, b0, acc, 0, 0, 0);
        acc = __builtin_amdgcn_mfma_f32_16x16x32_bf16(a1, b1, acc, 0, 0, 0);
#pragma unroll
        for (int reg = 0; reg < 4; ++reg) {
            int row = r0 + rt * 16 + quad * 4 + reg;
            if (row < N_NODES) {
                if (mr < 8) ssrcS[(size_t)row * 8 + mr] = acc[reg];
                else        sdstS[(size_t)row * 8 + (mr - 8)] = acc[reg];
            }
        }
    }
}

// ---------------- fused per-state gather: 8 nodes per wave, single pass ----
// Softmax stabilized by the SELF score (shift-invariant): w_e = exp(e - e_self),
// denom = 1 + sum(w_e). Relative scores are O(10) -> no overflow risk.
// One edge walk instead of two (no max pass).
template <int NK>
__global__ __launch_bounds__(128, 4) void fused_gather(
    const __bf16* __restrict__ hb, const int* __restrict__ row_ptr,
    const int* __restrict__ col_idx, const float* __restrict__ dinv,
    const float* __restrict__ cntf, const float* __restrict__ ssrcS,
    const float* __restrict__ sdstS, int soff, int doGS,
    __bf16* __restrict__ aggG, __bf16* __restrict__ aggS, __bf16* __restrict__ A) {
    int wid = blockIdx.x * 2 + (threadIdx.x >> 6);
    int lane = threadIdx.x & 63;
    int sub = lane >> 3, ln = lane & 7;
    int node = wid * 8 + sub;
    int beg = row_ptr[node], end = row_ptr[node + 1];

    float sd[NK], selfraw[NK];
    {
        float4 sv = *(const float4*)(ssrcS + (size_t)node * 8 + soff);
        float4 dvv = *(const float4*)(sdstS + (size_t)node * 8 + soff);
        float svv[4] = {sv.x, sv.y, sv.z, sv.w};
        float dvl[4] = {dvv.x, dvv.y, dvv.z, dvv.w};
#pragma unroll
        for (int t = 0; t < NK; ++t) {
            sd[t] = dvl[t];
            selfraw[t] = leaky(svv[t] + sd[t]);
        }
    }
    bf16x8 hsb = *(const bf16x8*)(hb + (size_t)node * 64 + ln * 8);
    float hs[8];
#pragma unroll
    for (int c = 0; c < 8; ++c) hs[c] = (float)hsb[c];

    float denoml[NK], acc[NK][8], accG[8], accS[8];
#pragma unroll
    for (int c = 0; c < 8; ++c) { accG[c] = 0.f; accS[c] = 0.f; }
#pragma unroll
    for (int t = 0; t < NK; ++t) {
        denoml[t] = 0.f;
#pragma unroll
        for (int c = 0; c < 8; ++c) acc[t][c] = hs[c];  // self term, w_self = 1
    }
    for (int base = beg; base < end; base += 8) {
        int e = base + ln;
        int col = 0;
        float dv = 0.f, wv[NK];
#pragma unroll
        for (int t = 0; t < NK; ++t) wv[t] = 0.f;
        if (e < end) {
            col = col_idx[e];
            dv = dinv[col];
            float4 sv = *(const float4*)(ssrcS + (size_t)col * 8 + soff);
            float svv[4] = {sv.x, sv.y, sv.z, sv.w};
#pragma unroll
            for (int t = 0; t < NK; ++t) {
                wv[t] = __expf(leaky(svv[t] + sd[t]) - selfraw[t]);
                denoml[t] += wv[t];
            }
        }
        int jcnt = end - base;
        if (jcnt > 8) jcnt = 8;
        int cs0 = __shfl(col, (sub << 3), 64);
        bf16x8 hx = *(const bf16x8*)(hb + (size_t)cs0 * 64 + ln * 8);
        for (int j = 0; j < jcnt; ++j) {
            bf16x8 hxn;
            if (j + 1 < jcnt) {
                int csn = __shfl(col, (sub << 3) | (j + 1), 64);
                hxn = *(const bf16x8*)(hb + (size_t)csn * 64 + ln * 8);
            }
            int srcl = (sub << 3) | j;
            float dvj = __shfl(dv, srcl, 64);
            float wj[NK];
#pragma unroll
            for (int t = 0; t < NK; ++t) wj[t] = __shfl(wv[t], srcl, 64);
#pragma unroll
            for (int c = 0; c < 8; ++c) {
                float f = (float)hx[c];
                accS[c] += f;
                accG[c] += dvj * f;
#pragma unroll
                for (int t = 0; t < NK; ++t) acc[t][c] += wj[t] * f;
            }
            hx = hxn;
        }
    }
    float denom[NK];
#pragma unroll
    for (int t = 0; t < NK; ++t) {
        float w = denoml[t];
#pragma unroll
        for (int off = 1; off < 8; off <<= 1) w += __shfl_xor(w, off, 64);
        denom[t] = w + 1.0f;
    }

    if (doGS) {
        float dvn = dinv[node];
        float cin = 1.0f / cntf[node];
        bf16x8 og, os;
#pragma unroll
        for (int c = 0; c < 8; ++c) {
            os[c] = (__bf16)(accS[c] * cin);
            og[c] = (__bf16)(dvn * accG[c] + dvn * dvn * hs[c]);
        }
        *(bf16x8*)(aggS + (size_t)node * 64 + ln * 8) = os;
        *(bf16x8*)(aggG + (size_t)node * 64 + ln * 8) = og;
    }
#pragma unroll
    for (int t = 0; t < NK; ++t) {
        bf16x8 oa;
        float inv = 1.0f / denom[t];
#pragma unroll
        for (int c = 0; c < 8; ++c) oa[c] = (__bf16)(acc[t][c] * inv);
        *(bf16x8*)(A + (size_t)t * N_NODES * 64 + (size_t)node * 64 + ln * 8) = oa;
    }
}

// ---------------- MFMA group GEMM ------------------------------------------
struct GArgs {
    const __bf16* G;
    const __bf16* S;
    const __bf16* Hb;
    const __bf16* A0;
    const __bf16* Wt;
    const float* bc;
    float* tg[4];
    __bf16* shadow_ptr;
    long long slot;
    int nk;
    int initmask;   // bit t: run starting at t does init-write
    int shadow_t;   // flush index writing the bf16 shadow (-1 none)
    int kidx[8];
    int tsel[8];
};

__global__ __launch_bounds__(256) void gemm_group(GArgs a) {
    __shared__ __bf16 Wl[64 * 264];
    int tid = threadIdx.x;
    int wave = tid >> 6, lane = tid & 63;
    int quad = lane >> 4, mr = lane & 15;
    int r0 = blockIdx.x * 128 + wave * 32;
    bf16x8 gf[2][2], sf[2][2], hf[2][2];
#pragma unroll
    for (int rt = 0; rt < 2; ++rt) {
        int r = r0 + rt * 16 + mr;
        if (r > N_NODES - 1) r = N_NODES - 1;
#pragma unroll
        for (int hh = 0; hh < 2; ++hh) {
            int colj = hh * 32 + (quad << 3);
            gf[rt][hh] = *(const bf16x8*)(a.G + (size_t)r * 64 + colj);
            sf[rt][hh] = *(const bf16x8*)(a.S + (size_t)r * 64 + colj);
            hf[rt][hh] = *(const bf16x8*)(a.Hb + (size_t)r * 64 + colj);
        }
    }
    floatx4 acc[2][4];
    float bsum[4];
#pragma unroll
    for (int rt = 0; rt < 2; ++rt)
#pragma unroll
        for (int ct = 0; ct < 4; ++ct) acc[rt][ct] = (floatx4){0.f, 0.f, 0.f, 0.f};
#pragma unroll
    for (int ct = 0; ct < 4; ++ct) bsum[ct] = 0.f;
    int runstart = 0;
    for (int t = 0; t < a.nk; ++t) {
        int k = a.kidx[t];
        __syncthreads();
        {
            const uint4* src = (const uint4*)(a.Wt + (size_t)k * 16384);
            for (int i = tid; i < 2048; i += 256) {
                int row = i >> 5, colj = (i & 31) << 3;
                *(uint4*)&Wl[row * 264 + colj] = src[i];
            }
        }
        __syncthreads();
        const __bf16* Ap = a.A0 + (size_t)t * a.slot;
        bf16x8 af[2][2];
#pragma unroll
        for (int rt = 0; rt < 2; ++rt) {
            int r = r0 + rt * 16 + mr;
            if (r > N_NODES - 1) r = N_NODES - 1;
#pragma unroll
            for (int hh = 0; hh < 2; ++hh)
                af[rt][hh] = *(const bf16x8*)(Ap + (size_t)r * 64 + hh * 32 + (quad << 3));
        }
        const float* bp = a.bc + k * 64;
#pragma unroll
        for (int ct = 0; ct < 4; ++ct) bsum[ct] += bp[ct * 16 + mr];
#pragma unroll
        for (int seg = 0; seg < 4; ++seg) {
#pragma unroll
            for (int hh = 0; hh < 2; ++hh) {
                int kt = seg * 2 + hh;
                bf16x8 a0 = (seg == 0) ? gf[0][hh] : (seg == 1) ? sf[0][hh]
                            : (seg == 2) ? hf[0][hh] : af[0][hh];
                bf16x8 a1 = (seg == 0) ? gf[1][hh] : (seg == 1) ? sf[1][hh]
                            : (seg == 2) ? hf[1][hh] : af[1][hh];
#pragma unroll
                for (int ct = 0; ct < 4; ++ct) {
                    bf16x8 bfr = *(const bf16x8*)&Wl[(ct * 16 + mr) * 264 + (kt << 5) + (quad << 3)];
                    acc[0][ct] = __builtin_amdgcn_mfma_f32_16x16x32_bf16(a0, bfr, acc[0][ct], 0, 0, 0);
                    acc[1][ct] = __builtin_amdgcn_mfma_f32_16x16x32_bf16(a1, bfr, acc[1][ct], 0, 0, 0);
                }
            }
        }
        bool flush = (t == a.nk - 1) || (a.tsel[t + 1] != a.tsel[t]);
        if (flush) {
            float* tgt = a.tg[a.tsel[t]];
            int init = (a.initmask >> runstart) & 1;
            bool shadow = (t == a.shadow_t);
            __bf16* sh = a.shadow_ptr;
#pragma unroll
            for (int rt = 0; rt < 2; ++rt) {
#pragma unroll
                for (int reg = 0; reg < 4; ++reg) {
                    int r = r0 + rt * 16 + quad * 4 + reg;
                    if (r < N_NODES) {
#pragma unroll
                        for (int ct = 0; ct < 4; ++ct) {
                            int c = ct * 16 + mr;
                            float v = acc[rt][ct][reg] + bsum[ct];
                            size_t idx = (size_t)r * 64 + c;
                            float nv = init ? v : (tgt[idx] + v);
                            tgt[idx] = nv;
                            if (shadow) sh[idx] = (__bf16)nv;
                        }
                    }
                }
            }
#pragma unroll
            for (int rt = 0; rt < 2; ++rt)
#pragma unroll
                for (int ct = 0; ct < 4; ++ct) acc[rt][ct] = (floatx4){0.f, 0.f, 0.f, 0.f};
#pragma unroll
            for (int ct = 0; ct < 4; ++ct) bsum[ct] = 0.f;
            runstart = t + 1;
        }
    }
}

extern "C" void kernel_launch(void* const* d_in, const int* in_sizes, int n_in,
                              void* d_out, int out_size, void* d_ws, size_t ws_size,
                              hipStream_t stream) {
    const float* x       = (const float*)d_in[0];
    const int*   ei      = (const int*)d_in[1];
    const float* alphas  = (const float*)d_in[2];
    const float* gcn_W   = (const float*)d_in[3];
    const float* gcn_b   = (const float*)d_in[4];
    const float* sage_Wl = (const float*)d_in[5];
    const float* sage_Wr = (const float*)d_in[6];
    const float* sage_b  = (const float*)d_in[7];
    const float* gat_W   = (const float*)d_in[8];
    const float* a_src   = (const float*)d_in[9];
    const float* a_dst   = (const float*)d_in[10];
    const float* gat_b   = (const float*)d_in[11];
    float* out = (float*)d_out;

    char* p = (char*)d_ws;
    auto alloc = [&](size_t bytes) -> char* {
        char* r = p;
        p += (bytes + 255) & ~(size_t)255;
        return r;
    };
    const size_t NCf = (size_t)N_NODES * CCH;
    const size_t NC32 = NCf * 4;
    const size_t NC16 = NCf * 2;
    float* sb[3];
    sb[0] = (float*)alloc(NC32);
    sb[1] = (float*)alloc(NC32);
    sb[2] = (float*)alloc(NC32);
    __bf16* hbuf[4];  // bf16 shadows of x, sb0, sb1, sb2
    for (int i = 0; i < 4; ++i) hbuf[i] = (__bf16*)alloc(NC16);
    __bf16* aggG = (__bf16*)alloc(NC16);
    __bf16* aggS = (__bf16*)alloc(NC16);
    float* ssrcS = (float*)alloc((size_t)N_NODES * 8 * 4);
    float* sdstS = (float*)alloc((size_t)N_NODES * 8 * 4);
    float* dinv  = (float*)alloc(N_NODES * 4);
    float* cntf  = (float*)alloc(N_NODES * 4);
    int* row_ptr = (int*)alloc((N_NODES + 1) * 4);
    int* col_idx = (int*)alloc((size_t)N_EDGES * 4);
    unsigned long long* pairs = (unsigned long long*)alloc((size_t)N_EDGES * 8);
    int* bcount  = (int*)alloc(NBUCK * 4);
    int* bfill   = (int*)alloc(NBUCK * 16 * 4);
    int* bbase   = (int*)alloc((NBUCK + 1) * 4);
    __bf16* Wt   = (__bf16*)alloc((size_t)N_MIX * 16384 * 2);
    float* bcv   = (float*)alloc(N_MIX * 64 * 4);
    float* vs    = (float*)alloc(N_MIX * 64 * 4);
    float* vd    = (float*)alloc(N_MIX * 64 * 4);
    __bf16* Vph  = (__bf16*)alloc(4 * 1024 * 2);

    size_t used = (size_t)(p - (char*)d_ws);
    int navail = (int)((ws_size > used) ? ((ws_size - used) / NC16) : 0);
    if (navail < 1) navail = 1;
    if (navail > 8) navail = 8;
    __bf16* Abuf = (__bf16*)alloc((size_t)navail * NC16);

    // zero bcount + bfill (contiguous-ish: two memsets)
    hipMemsetAsync(bcount, 0, NBUCK * 4, stream);
    hipMemsetAsync(bfill, 0, NBUCK * 16 * 4, stream);

    prep_weights<<<N_MIX, 256, 0, stream>>>(alphas, gcn_W, gcn_b, sage_Wl, sage_Wr, sage_b,
                                            gat_W, a_src, a_dst, gat_b, Wt, bcv, vs, vd);
    // phase k-sets: {0,1,2,3,5,6,9,10} / {4,7,11} / {8,12} / {13}
    prep_scoreV<<<4, 256, 0, stream>>>(vs, vd, Vph, 0xA9653210u, 0xB74u, 0xC8u, 0xDu, 0x1238u);
    convert_bf16<<<(int)((NCf / 4 + 255) / 256), 256, 0, stream>>>((const float4*)x, hbuf[0],
                                                                   (int)(NCf / 4));
    bucket_count<<<256, 256, 0, stream>>>(ei, bcount);
    bucket_scan<<<1, 256, 0, stream>>>(bcount, bbase, row_ptr);
    bucket_scatter<<<(N_EDGES + 255) / 256, 256, 0, stream>>>(ei, bbase, bfill, pairs);
    bucket_sort<<<NBUCK, 256, 0, stream>>>(pairs, bbase, row_ptr, col_idx, dinv, cntf);

    const int AGG_GRID = N_NODES / 16;            // 3125 blocks x 128 thr
    const int GEMM_GRID = (N_NODES + 127) / 128;  // 391

    float* targ[4] = {sb[0], sb[1], sb[2], out};
    struct Phase { int nk; int ks[8]; int tg[8]; };
    const Phase ph[4] = {
        {8, {0, 1, 2, 3, 5, 6, 9, 10}, {0, 0, 1, 1, 2, 2, 3, 3}},
        {3, {4, 7, 11, 0, 0, 0, 0, 0}, {1, 2, 3, 0, 0, 0, 0, 0}},
        {2, {8, 12, 0, 0, 0, 0, 0, 0}, {2, 3, 0, 0, 0, 0, 0, 0}},
        {1, {13, 0, 0, 0, 0, 0, 0, 0}, {3, 0, 0, 0, 0, 0, 0, 0}},
    };

    auto launch_gather = [&](int nkk, const __bf16* hb, int soff, int doGS, __bf16* Aslot) {
        switch (nkk) {
            case 4: fused_gather<4><<<AGG_GRID, 128, 0, stream>>>(hb, row_ptr, col_idx, dinv, cntf, ssrcS, sdstS, soff, doGS, aggG, aggS, Aslot); break;
            case 3: fused_gather<3><<<AGG_GRID, 128, 0, stream>>>(hb, row_ptr, col_idx, dinv, cntf, ssrcS, sdstS, soff, doGS, aggG, aggS, Aslot); break;
            case 2: fused_gather<2><<<AGG_GRID, 128, 0, stream>>>(hb, row_ptr, col_idx, dinv, cntf, ssrcS, sdstS, soff, doGS, aggG, aggS, Aslot); break;
            default: fused_gather<1><<<AGG_GRID, 128, 0, stream>>>(hb, row_ptr, col_idx, dinv, cntf, ssrcS, sdstS, soff, doGS, aggG, aggS, Aslot); break;
        }
    };
    auto make_gemm = [&](const Phase& P, const __bf16* hb, int kstart, int g) {
        GArgs ga;
        ga.G = aggG; ga.S = aggS; ga.Hb = hb; ga.A0 = Abuf;
        ga.Wt = Wt; ga.bc = bcv;
        for (int i = 0; i < 4; ++i) ga.tg[i] = targ[i];
        ga.slot = (long long)NCf;
        ga.nk = g;
        ga.initmask = 0;
        ga.shadow_t = -1;
        ga.shadow_ptr = hbuf[0];
        for (int j = 0; j < g; ++j) {
            int k = P.ks[kstart + j];
            ga.kidx[j] = k;
            ga.tsel[j] = P.tg[kstart + j];
            if (k == 0 || k == 2 || k == 5 || k == 9) ga.initmask |= (1 << j);
            if (k == 1) { ga.shadow_t = j; ga.shadow_ptr = hbuf[1]; }
            if (k == 4) { ga.shadow_t = j; ga.shadow_ptr = hbuf[2]; }
            if (k == 8) { ga.shadow_t = j; ga.shadow_ptr = hbuf[3]; }
        }
        for (int j = g; j < 8; ++j) { ga.kidx[j] = 0; ga.tsel[j] = (j > 0) ? ga.tsel[j - 1] : 0; }
        gemm_group<<<GEMM_GRID, 256, 0, stream>>>(ga);
    };

    for (int st = 0; st < 4; ++st) {
        const Phase& P = ph[st];
        const __bf16* hb = hbuf[st];
        score_mfma<<<GEMM_GRID, 256, 0, stream>>>(hb, Vph + st * 1024, ssrcS, sdstS);
        if (navail >= P.nk) {
            // all gathers into consecutive slots, then ONE gemm_group
            int done = 0;
            while (done < P.nk) {
                int g = P.nk - done;
                if (g > 4) g = 4;
                launch_gather(g, hb, done, (done == 0) ? 1 : 0, Abuf + (size_t)done * NCf);
                done += g;
            }
            make_gemm(P, hb, 0, P.nk);
        } else {
            int gs = (navail < 4) ? navail : 4;
            for (int done = 0; done < P.nk;) {
                int g = gs;
                if (g > P.nk - done) g = P.nk - done;
                launch_gather(g, hb, done, (done == 0) ? 1 : 0, Abuf);
                make_gemm(P, hb, done, g);
                done += g;
            }
        }
    }
}

// Round 10
// 462.951 us; speedup vs baseline: 1.3424x; 1.1522x over previous
//
#include <hip/hip_runtime.h>

#define N_NODES 50000
#define N_EDGES 800000
#define CCH 64
#define N_MIX 14
#define NBUCK 196   // ceil(50000/256)
#define BCAP 6144   // per-bucket edge capacity (mean ~4082)
#define ECHUNK 3125 // 800000 / 256 blocks, exact

typedef __bf16 bf16x8 __attribute__((ext_vector_type(8)));
typedef float floatx4 __attribute__((ext_vector_type(4)));

__device__ __forceinline__ float leaky(float x) {
    return fmaxf(x, 0.2f * x);
}

// ---------------- weight prep --------------------------------------------
// Wt[k] : 64(out-col) x 256(in-dim) bf16, transposed, scale-folded.
//   j<64: g*w0*gcn_W ; j<128: g*w1*sage_Wl ;
//   j<192: g*w1*sage_Wr + I*(g*w3 + (k>=11 ? 0.25 : 0)) ; j<256: g*w2*gat_W
// g=0.25 for k>=9 (final mean folded); +0.25*I for k in {11,12,13} folds
// final_mean's 0.25*(s2+s3+s4) since those k's H-input IS s2/s3/s4.
__global__ void prep_weights(const float* __restrict__ alphas,
                             const float* __restrict__ gcn_W, const float* __restrict__ gcn_b,
                             const float* __restrict__ sage_Wl, const float* __restrict__ sage_Wr,
                             const float* __restrict__ sage_b, const float* __restrict__ gat_Wp,
                             const float* __restrict__ a_src, const float* __restrict__ a_dst,
                             const float* __restrict__ gat_b,
                             __bf16* __restrict__ Wt, float* __restrict__ bc,
                             float* __restrict__ vs, float* __restrict__ vd) {
    int k = blockIdx.x;
    __shared__ float w[5];
    if (threadIdx.x == 0) {
        float a[5], m = -1e30f, s = 0.f;
        for (int i = 0; i < 5; ++i) { a[i] = alphas[k * 5 + i]; m = fmaxf(m, a[i]); }
        for (int i = 0; i < 5; ++i) { a[i] = __expf(a[i] - m); s += a[i]; }
        for (int i = 0; i < 5; ++i) w[i] = a[i] / s;
    }
    __syncthreads();
    float gamma = (k >= 9) ? 0.25f : 1.0f;
    float w0 = gamma * w[0], w1 = gamma * w[1], w2 = gamma * w[2], w3 = gamma * w[3];
    float idext = (k >= 11) ? 0.25f : 0.f;
    for (int idx = threadIdx.x; idx < 64 * 256; idx += blockDim.x) {
        int c = idx >> 8, j = idx & 255;
        float v;
        if (j < 64)       v = w0 * gcn_W[k * 4096 + j * 64 + c];
        else if (j < 128) v = w1 * sage_Wl[k * 4096 + (j - 64) * 64 + c];
        else if (j < 192) {
            int jj = j - 128;
            v = w1 * sage_Wr[k * 4096 + jj * 64 + c];
            if (jj == c) v += w3 + idext;
        } else {
            v = w2 * gat_Wp[k * 4096 + (j - 192) * 64 + c];
        }
        Wt[(size_t)k * 16384 + idx] = (__bf16)v;
    }
    if (threadIdx.x < 64) {
        int r = threadIdx.x;
        bc[k * 64 + r] = gamma * (w[0] * gcn_b[k * 64 + r] + w[1] * sage_b[k * 64 + r] +
                                  w[2] * gat_b[k * 64 + r]);
        float s1 = 0.f, s2 = 0.f;
        for (int j = 0; j < 64; ++j) {
            float wv_ = gat_Wp[k * 4096 + r * 64 + j];
            s1 += wv_ * a_src[k * 64 + j];
            s2 += wv_ * a_dst[k * 64 + j];
        }
        vs[k * 64 + r] = s1;
        vd[k * 64 + r] = s2;
    }
}

// Per-phase score V matrix: Vph[p] is 16x64 bf16. n<8: vs of phase-k slot n;
// n>=8: vd of slot n-8; zero for slots >= nk.
__global__ void prep_scoreV(const float* __restrict__ vs, const float* __restrict__ vd,
                            __bf16* __restrict__ Vph,
                            unsigned km0, unsigned km1, unsigned km2, unsigned km3,
                            unsigned nks) {
    int p = blockIdx.x;
    unsigned km = (p == 0) ? km0 : (p == 1) ? km1 : (p == 2) ? km2 : km3;
    int nk = (nks >> (p * 4)) & 15;
    for (int idx = threadIdx.x; idx < 1024; idx += blockDim.x) {
        int n = idx >> 6, kk = idx & 63;
        int t = n & 7;
        float v = 0.f;
        if (t < nk) {
            int k = (km >> (4 * t)) & 15;
            v = (n < 8) ? vs[k * 64 + kk] : vd[k * 64 + kk];
        }
        Vph[p * 1024 + n * 64 + kk] = (__bf16)v;
    }
}

__global__ void convert_bf16(const float4* __restrict__ src, __bf16* __restrict__ dst, int n4) {
    int i = blockIdx.x * blockDim.x + threadIdx.x;
    if (i < n4) {
        float4 v = src[i];
        dst[i * 4 + 0] = (__bf16)v.x;
        dst[i * 4 + 1] = (__bf16)v.y;
        dst[i * 4 + 2] = (__bf16)v.z;
        dst[i * 4 + 3] = (__bf16)v.w;
    }
}

// ---------------- CSR build via bucket counting sort -----------------------
// bucket b = dst >> 8 covers nodes [b*256, b*256+255].
__global__ __launch_bounds__(256) void bucket_count(const int* __restrict__ ei,
                                                    int* __restrict__ bcount) {
    __shared__ int h[NBUCK];
    for (int i = threadIdx.x; i < NBUCK; i += 256) h[i] = 0;
    __syncthreads();
    int e0 = blockIdx.x * ECHUNK;
    for (int i = threadIdx.x; i < ECHUNK; i += 256)
        atomicAdd(&h[ei[N_EDGES + e0 + i] >> 8], 1);
    __syncthreads();
    for (int i = threadIdx.x; i < NBUCK; i += 256)
        if (h[i]) atomicAdd(&bcount[i], h[i]);
}

__global__ __launch_bounds__(256) void bucket_scan(const int* __restrict__ bcount,
                                                   int* __restrict__ bbase,
                                                   int* __restrict__ row_ptr) {
    __shared__ int s[256];
    int t = threadIdx.x;
    int v = (t < NBUCK) ? bcount[t] : 0;
    s[t] = v;
    __syncthreads();
    for (int o = 1; o < 256; o <<= 1) {
        int t2 = (t >= o) ? s[t - o] : 0;
        __syncthreads();
        s[t] += t2;
        __syncthreads();
    }
    if (t < NBUCK) bbase[t + 1] = s[t];
    if (t == 0) { bbase[0] = 0; row_ptr[N_NODES] = N_EDGES; }
}

// Per-block reservation scatter: each block owns ECHUNK edges. LDS histogram,
// one global atomic per (block,bucket) reserves a contiguous run, then the
// block scatters packed (dlow<<16 | src) words into its run (line-local
// writes, one XCD per line -> single HBM writeback). src<50000 fits 16 bits.
__global__ __launch_bounds__(256) void bucket_scatter(const int* __restrict__ ei,
                                                      const int* __restrict__ bbase,
                                                      int* __restrict__ bfill,
                                                      unsigned* __restrict__ pairs) {
    __shared__ int lh[NBUCK], lbase[NBUCK], lcur[NBUCK];
    int tid = threadIdx.x;
    int e0 = blockIdx.x * ECHUNK;
    for (int i = tid; i < NBUCK; i += 256) { lh[i] = 0; lcur[i] = 0; }
    __syncthreads();
    for (int i = tid; i < ECHUNK; i += 256)
        atomicAdd(&lh[ei[N_EDGES + e0 + i] >> 8], 1);
    __syncthreads();
    for (int i = tid; i < NBUCK; i += 256)
        lbase[i] = bbase[i] + ((lh[i] > 0) ? atomicAdd(&bfill[i], lh[i]) : 0);
    __syncthreads();
    for (int i = tid; i < ECHUNK; i += 256) {
        int s = ei[e0 + i];
        int d = ei[N_EDGES + e0 + i];
        int b = d >> 8;
        int pos = atomicAdd(&lcur[b], 1);
        pairs[lbase[b] + pos] = (unsigned)s | ((unsigned)(d & 255) << 16);
    }
}

__global__ __launch_bounds__(256) void bucket_sort(const unsigned* __restrict__ pairs,
                                                   const int* __restrict__ bbase,
                                                   int* __restrict__ row_ptr,
                                                   int* __restrict__ col_idx,
                                                   float* __restrict__ dinv,
                                                   float* __restrict__ cntf) {
    int b = blockIdx.x;
    __shared__ unsigned buf[BCAP];
    __shared__ int hist[256], off[256], cur[256];
    int tid = threadIdx.x;
    hist[tid] = 0;
    __syncthreads();
    int base = bbase[b], cnt = bbase[b + 1] - base;
    if (cnt > BCAP) cnt = BCAP;  // statistically impossible; hard safety
    for (int i = tid; i < cnt; i += 256) {
        unsigned pr = pairs[(size_t)base + i];
        buf[i] = pr;
        atomicAdd(&hist[(pr >> 16) & 255], 1);
    }
    __syncthreads();
    int v = hist[tid];
    off[tid] = v;
    __syncthreads();
    for (int o = 1; o < 256; o <<= 1) {
        int t2 = (tid >= o) ? off[tid - o] : 0;
        __syncthreads();
        off[tid] += t2;
        __syncthreads();
    }
    int excl = off[tid] - v;
    int node = b * 256 + tid;
    if (node < N_NODES) {
        row_ptr[node] = base + excl;
        dinv[node] = rsqrtf((float)(v + 1));
        cntf[node] = (float)(v > 0 ? v : 1);
    }
    cur[tid] = excl;
    __syncthreads();
    for (int i = tid; i < cnt; i += 256) {
        unsigned pr = buf[i];
        int ln = (pr >> 16) & 255;
        int pos = atomicAdd(&cur[ln], 1);
        col_idx[base + pos] = (int)(pr & 0xffffu);
    }
}

// ---------------- MFMA score kernel ----------------------------------------
// scores(50000x16) = hb(50000x64) @ V^T. V is 16x64 (n,k). One wave = 32 rows.
__global__ __launch_bounds__(256) void score_mfma(const __bf16* __restrict__ hb,
                                                  const __bf16* __restrict__ V,
                                                  float* __restrict__ ssrcS,
                                                  float* __restrict__ sdstS) {
    int tid = threadIdx.x;
    int wave = tid >> 6, lane = tid & 63;
    int quad = lane >> 4, mr = lane & 15;
    int r0 = blockIdx.x * 128 + wave * 32;
    bf16x8 b0 = *(const bf16x8*)(V + mr * 64 + (quad << 3));
    bf16x8 b1 = *(const bf16x8*)(V + mr * 64 + 32 + (quad << 3));
#pragma unroll
    for (int rt = 0; rt < 2; ++rt) {
        int r = r0 + rt * 16 + mr;
        if (r > N_NODES - 1) r = N_NODES - 1;
        bf16x8 a0 = *(const bf16x8*)(hb + (size_t)r * 64 + (quad << 3));
        bf16x8 a1 = *(const bf16x8*)(hb + (size_t)r * 64 + 32 + (quad << 3));
        floatx4 acc = (floatx4){0.f, 0.f, 0.f, 0.f};
        acc = __builtin_amdgcn_mfma_f32_16x16x32_bf16(a0, b0, acc, 0, 0, 0);
        acc = __builtin_amdgcn_mfma_f32_16x16x32_bf16(a1, b1, acc, 0, 0, 0);
#pragma unroll
        for (int reg = 0; reg < 4; ++reg) {
            int row = r0 + rt * 16 + quad * 4 + reg;
            if (row < N_NODES) {
                if (mr < 8) ssrcS[(size_t)row * 8 + mr] = acc[reg];
                else        sdstS[(size_t)row * 8 + (mr - 8)] = acc[reg];
            }
        }
    }
}

// ---------------- fused per-state gather: 8 nodes per wave, single pass ----
// Softmax stabilized by the SELF score (shift-invariant): w_e = exp(e - e_self),
// denom = 1 + sum(w_e).
template <int NK>
__global__ __launch_bounds__(128, 4) void fused_gather(
    const __bf16* __restrict__ hb, const int* __restrict__ row_ptr,
    const int* __restrict__ col_idx, const float* __restrict__ dinv,
    const float* __restrict__ cntf, const float* __restrict__ ssrcS,
    const float* __restrict__ sdstS, int soff, int doGS,
    __bf16* __restrict__ aggG, __bf16* __restrict__ aggS, __bf16* __restrict__ A) {
    int wid = blockIdx.x * 2 + (threadIdx.x >> 6);
    int lane = threadIdx.x & 63;
    int sub = lane >> 3, ln = lane & 7;
    int node = wid * 8 + sub;
    int beg = row_ptr[node], end = row_ptr[node + 1];

    float sd[NK], selfraw[NK];
    {
        float4 sv = *(const float4*)(ssrcS + (size_t)node * 8 + soff);
        float4 dvv = *(const float4*)(sdstS + (size_t)node * 8 + soff);
        float svv[4] = {sv.x, sv.y, sv.z, sv.w};
        float dvl[4] = {dvv.x, dvv.y, dvv.z, dvv.w};
#pragma unroll
        for (int t = 0; t < NK; ++t) {
            sd[t] = dvl[t];
            selfraw[t] = leaky(svv[t] + sd[t]);
        }
    }
    bf16x8 hsb = *(const bf16x8*)(hb + (size_t)node * 64 + ln * 8);
    float hs[8];
#pragma unroll
    for (int c = 0; c < 8; ++c) hs[c] = (float)hsb[c];

    float denoml[NK], acc[NK][8], accG[8], accS[8];
#pragma unroll
    for (int c = 0; c < 8; ++c) { accG[c] = 0.f; accS[c] = 0.f; }
#pragma unroll
    for (int t = 0; t < NK; ++t) {
        denoml[t] = 0.f;
#pragma unroll
        for (int c = 0; c < 8; ++c) acc[t][c] = hs[c];  // self term, w_self = 1
    }
    for (int base = beg; base < end; base += 8) {
        int e = base + ln;
        int col = 0;
        float dv = 0.f, wv[NK];
#pragma unroll
        for (int t = 0; t < NK; ++t) wv[t] = 0.f;
        if (e < end) {
            col = col_idx[e];
            dv = dinv[col];
            float4 sv = *(const float4*)(ssrcS + (size_t)col * 8 + soff);
            float svv[4] = {sv.x, sv.y, sv.z, sv.w};
#pragma unroll
            for (int t = 0; t < NK; ++t) {
                wv[t] = __expf(leaky(svv[t] + sd[t]) - selfraw[t]);
                denoml[t] += wv[t];
            }
        }
        int jcnt = end - base;
        if (jcnt > 8) jcnt = 8;
        int cs0 = __shfl(col, (sub << 3), 64);
        bf16x8 hx = *(const bf16x8*)(hb + (size_t)cs0 * 64 + ln * 8);
        for (int j = 0; j < jcnt; ++j) {
            bf16x8 hxn;
            if (j + 1 < jcnt) {
                int csn = __shfl(col, (sub << 3) | (j + 1), 64);
                hxn = *(const bf16x8*)(hb + (size_t)csn * 64 + ln * 8);
            }
            int srcl = (sub << 3) | j;
            float dvj = __shfl(dv, srcl, 64);
            float wj[NK];
#pragma unroll
            for (int t = 0; t < NK; ++t) wj[t] = __shfl(wv[t], srcl, 64);
#pragma unroll
            for (int c = 0; c < 8; ++c) {
                float f = (float)hx[c];
                accS[c] += f;
                accG[c] += dvj * f;
#pragma unroll
                for (int t = 0; t < NK; ++t) acc[t][c] += wj[t] * f;
            }
            hx = hxn;
        }
    }
    float denom[NK];
#pragma unroll
    for (int t = 0; t < NK; ++t) {
        float w = denoml[t];
#pragma unroll
        for (int off = 1; off < 8; off <<= 1) w += __shfl_xor(w, off, 64);
        denom[t] = w + 1.0f;
    }

    if (doGS) {
        float dvn = dinv[node];
        float cin = 1.0f / cntf[node];
        bf16x8 og, os;
#pragma unroll
        for (int c = 0; c < 8; ++c) {
            os[c] = (__bf16)(accS[c] * cin);
            og[c] = (__bf16)(dvn * accG[c] + dvn * dvn * hs[c]);
        }
        *(bf16x8*)(aggS + (size_t)node * 64 + ln * 8) = os;
        *(bf16x8*)(aggG + (size_t)node * 64 + ln * 8) = og;
    }
#pragma unroll
    for (int t = 0; t < NK; ++t) {
        bf16x8 oa;
        float inv = 1.0f / denom[t];
#pragma unroll
        for (int c = 0; c < 8; ++c) oa[c] = (__bf16)(acc[t][c] * inv);
        *(bf16x8*)(A + (size_t)t * N_NODES * 64 + (size_t)node * 64 + ln * 8) = oa;
    }
}

// ---------------- MFMA group GEMM ------------------------------------------
struct GArgs {
    const __bf16* G;
    const __bf16* S;
    const __bf16* Hb;
    const __bf16* A0;
    const __bf16* Wt;
    const float* bc;
    float* tg[4];
    __bf16* shadow_ptr;
    long long slot;
    int nk;
    int initmask;   // bit t: run starting at t does init-write
    int shadow_t;   // flush index writing the bf16 shadow (-1 none)
    int kidx[8];
    int tsel[8];
};

__global__ __launch_bounds__(256) void gemm_group(GArgs a) {
    __shared__ __bf16 Wl[64 * 264];
    int tid = threadIdx.x;
    int wave = tid >> 6, lane = tid & 63;
    int quad = lane >> 4, mr = lane & 15;
    int r0 = blockIdx.x * 128 + wave * 32;
    bf16x8 gf[2][2], sf[2][2], hf[2][2];
#pragma unroll
    for (int rt = 0; rt < 2; ++rt) {
        int r = r0 + rt * 16 + mr;
        if (r > N_NODES - 1) r = N_NODES - 1;
#pragma unroll
        for (int hh = 0; hh < 2; ++hh) {
            int colj = hh * 32 + (quad << 3);
            gf[rt][hh] = *(const bf16x8*)(a.G + (size_t)r * 64 + colj);
            sf[rt][hh] = *(const bf16x8*)(a.S + (size_t)r * 64 + colj);
            hf[rt][hh] = *(const bf16x8*)(a.Hb + (size_t)r * 64 + colj);
        }
    }
    floatx4 acc[2][4];
    float bsum[4];
#pragma unroll
    for (int rt = 0; rt < 2; ++rt)
#pragma unroll
        for (int ct = 0; ct < 4; ++ct) acc[rt][ct] = (floatx4){0.f, 0.f, 0.f, 0.f};
#pragma unroll
    for (int ct = 0; ct < 4; ++ct) bsum[ct] = 0.f;
    int runstart = 0;
    for (int t = 0; t < a.nk; ++t) {
        int k = a.kidx[t];
        __syncthreads();
        {
            const uint4* src = (const uint4*)(a.Wt + (size_t)k * 16384);
            for (int i = tid; i < 2048; i += 256) {
                int row = i >> 5, colj = (i & 31) << 3;
                *(uint4*)&Wl[row * 264 + colj] = src[i];
            }
        }
        __syncthreads();
        const __bf16* Ap = a.A0 + (size_t)t * a.slot;
        bf16x8 af[2][2];
#pragma unroll
        for (int rt = 0; rt < 2; ++rt) {
            int r = r0 + rt * 16 + mr;
            if (r > N_NODES - 1) r = N_NODES - 1;
#pragma unroll
            for (int hh = 0; hh < 2; ++hh)
                af[rt][hh] = *(const bf16x8*)(Ap + (size_t)r * 64 + hh * 32 + (quad << 3));
        }
        const float* bp = a.bc + k * 64;
#pragma unroll
        for (int ct = 0; ct < 4; ++ct) bsum[ct] += bp[ct * 16 + mr];
#pragma unroll
        for (int seg = 0; seg < 4; ++seg) {
#pragma unroll
            for (int hh = 0; hh < 2; ++hh) {
                int kt = seg * 2 + hh;
                bf16x8 a0 = (seg == 0) ? gf[0][hh] : (seg == 1) ? sf[0][hh]
                            : (seg == 2) ? hf[0][hh] : af[0][hh];
                bf16x8 a1 = (seg == 0) ? gf[1][hh] : (seg == 1) ? sf[1][hh]
                            : (seg == 2) ? hf[1][hh] : af[1][hh];
#pragma unroll
                for (int ct = 0; ct < 4; ++ct) {
                    bf16x8 bfr = *(const bf16x8*)&Wl[(ct * 16 + mr) * 264 + (kt << 5) + (quad << 3)];
                    acc[0][ct] = __builtin_amdgcn_mfma_f32_16x16x32_bf16(a0, bfr, acc[0][ct], 0, 0, 0);
                    acc[1][ct] = __builtin_amdgcn_mfma_f32_16x16x32_bf16(a1, bfr, acc[1][ct], 0, 0, 0);
                }
            }
        }
        bool flush = (t == a.nk - 1) || (a.tsel[t + 1] != a.tsel[t]);
        if (flush) {
            float* tgt = a.tg[a.tsel[t]];
            int init = (a.initmask >> runstart) & 1;
            bool shadow = (t == a.shadow_t);
            __bf16* sh = a.shadow_ptr;
#pragma unroll
            for (int rt = 0; rt < 2; ++rt) {
#pragma unroll
                for (int reg = 0; reg < 4; ++reg) {
                    int r = r0 + rt * 16 + quad * 4 + reg;
                    if (r < N_NODES) {
#pragma unroll
                        for (int ct = 0; ct < 4; ++ct) {
                            int c = ct * 16 + mr;
                            float v = acc[rt][ct][reg] + bsum[ct];
                            size_t idx = (size_t)r * 64 + c;
                            float nv = init ? v : (tgt[idx] + v);
                            tgt[idx] = nv;
                            if (shadow) sh[idx] = (__bf16)nv;
                        }
                    }
                }
            }
#pragma unroll
            for (int rt = 0; rt < 2; ++rt)
#pragma unroll
                for (int ct = 0; ct < 4; ++ct) acc[rt][ct] = (floatx4){0.f, 0.f, 0.f, 0.f};
#pragma unroll
            for (int ct = 0; ct < 4; ++ct) bsum[ct] = 0.f;
            runstart = t + 1;
        }
    }
}

extern "C" void kernel_launch(void* const* d_in, const int* in_sizes, int n_in,
                              void* d_out, int out_size, void* d_ws, size_t ws_size,
                              hipStream_t stream) {
    const float* x       = (const float*)d_in[0];
    const int*   ei      = (const int*)d_in[1];
    const float* alphas  = (const float*)d_in[2];
    const float* gcn_W   = (const float*)d_in[3];
    const float* gcn_b   = (const float*)d_in[4];
    const float* sage_Wl = (const float*)d_in[5];
    const float* sage_Wr = (const float*)d_in[6];
    const float* sage_b  = (const float*)d_in[7];
    const float* gat_W   = (const float*)d_in[8];
    const float* a_src   = (const float*)d_in[9];
    const float* a_dst   = (const float*)d_in[10];
    const float* gat_b   = (const float*)d_in[11];
    float* out = (float*)d_out;

    char* p = (char*)d_ws;
    auto alloc = [&](size_t bytes) -> char* {
        char* r = p;
        p += (bytes + 255) & ~(size_t)255;
        return r;
    };
    const size_t NCf = (size_t)N_NODES * CCH;
    const size_t NC32 = NCf * 4;
    const size_t NC16 = NCf * 2;
    float* sb[3];
    sb[0] = (float*)alloc(NC32);
    sb[1] = (float*)alloc(NC32);
    sb[2] = (float*)alloc(NC32);
    __bf16* hbuf[4];  // bf16 shadows of x, sb0, sb1, sb2
    for (int i = 0; i < 4; ++i) hbuf[i] = (__bf16*)alloc(NC16);
    __bf16* aggG = (__bf16*)alloc(NC16);
    __bf16* aggS = (__bf16*)alloc(NC16);
    float* ssrcS = (float*)alloc((size_t)N_NODES * 8 * 4);
    float* sdstS = (float*)alloc((size_t)N_NODES * 8 * 4);
    float* dinv  = (float*)alloc(N_NODES * 4);
    float* cntf  = (float*)alloc(N_NODES * 4);
    int* row_ptr = (int*)alloc((N_NODES + 1) * 4);
    int* col_idx = (int*)alloc((size_t)N_EDGES * 4);
    unsigned* pairs = (unsigned*)alloc((size_t)N_EDGES * 4);
    int* bcount  = (int*)alloc(NBUCK * 4);
    int* bfill   = (int*)alloc(NBUCK * 4);
    int* bbase   = (int*)alloc((NBUCK + 1) * 4);
    __bf16* Wt   = (__bf16*)alloc((size_t)N_MIX * 16384 * 2);
    float* bcv   = (float*)alloc(N_MIX * 64 * 4);
    float* vs    = (float*)alloc(N_MIX * 64 * 4);
    float* vd    = (float*)alloc(N_MIX * 64 * 4);
    __bf16* Vph  = (__bf16*)alloc(4 * 1024 * 2);

    size_t used = (size_t)(p - (char*)d_ws);
    int navail = (int)((ws_size > used) ? ((ws_size - used) / NC16) : 0);
    if (navail < 1) navail = 1;
    if (navail > 8) navail = 8;
    __bf16* Abuf = (__bf16*)alloc((size_t)navail * NC16);

    hipMemsetAsync(bcount, 0, NBUCK * 4, stream);
    hipMemsetAsync(bfill, 0, NBUCK * 4, stream);

    prep_weights<<<N_MIX, 256, 0, stream>>>(alphas, gcn_W, gcn_b, sage_Wl, sage_Wr, sage_b,
                                            gat_W, a_src, a_dst, gat_b, Wt, bcv, vs, vd);
    // phase k-sets: {0,1,2,3,5,6,9,10} / {4,7,11} / {8,12} / {13}
    prep_scoreV<<<4, 256, 0, stream>>>(vs, vd, Vph, 0xA9653210u, 0xB74u, 0xC8u, 0xDu, 0x1238u);
    convert_bf16<<<(int)((NCf / 4 + 255) / 256), 256, 0, stream>>>((const float4*)x, hbuf[0],
                                                                   (int)(NCf / 4));
    bucket_count<<<256, 256, 0, stream>>>(ei, bcount);
    bucket_scan<<<1, 256, 0, stream>>>(bcount, bbase, row_ptr);
    bucket_scatter<<<256, 256, 0, stream>>>(ei, bbase, bfill, pairs);
    bucket_sort<<<NBUCK, 256, 0, stream>>>(pairs, bbase, row_ptr, col_idx, dinv, cntf);

    const int AGG_GRID = N_NODES / 16;            // 3125 blocks x 128 thr
    const int GEMM_GRID = (N_NODES + 127) / 128;  // 391

    float* targ[4] = {sb[0], sb[1], sb[2], out};
    struct Phase { int nk; int ks[8]; int tg[8]; };
    const Phase ph[4] = {
        {8, {0, 1, 2, 3, 5, 6, 9, 10}, {0, 0, 1, 1, 2, 2, 3, 3}},
        {3, {4, 7, 11, 0, 0, 0, 0, 0}, {1, 2, 3, 0, 0, 0, 0, 0}},
        {2, {8, 12, 0, 0, 0, 0, 0, 0}, {2, 3, 0, 0, 0, 0, 0, 0}},
        {1, {13, 0, 0, 0, 0, 0, 0, 0}, {3, 0, 0, 0, 0, 0, 0, 0}},
    };

    auto launch_gather = [&](int nkk, const __bf16* hb, int soff, int doGS, __bf16* Aslot) {
        switch (nkk) {
            case 4: fused_gather<4><<<AGG_GRID, 128, 0, stream>>>(hb, row_ptr, col_idx, dinv, cntf, ssrcS, sdstS, soff, doGS, aggG, aggS, Aslot); break;
            case 3: fused_gather<3><<<AGG_GRID, 128, 0, stream>>>(hb, row_ptr, col_idx, dinv, cntf, ssrcS, sdstS, soff, doGS, aggG, aggS, Aslot); break;
            case 2: fused_gather<2><<<AGG_GRID, 128, 0, stream>>>(hb, row_ptr, col_idx, dinv, cntf, ssrcS, sdstS, soff, doGS, aggG, aggS, Aslot); break;
            default: fused_gather<1><<<AGG_GRID, 128, 0, stream>>>(hb, row_ptr, col_idx, dinv, cntf, ssrcS, sdstS, soff, doGS, aggG, aggS, Aslot); break;
        }
    };
    auto make_gemm = [&](const Phase& P, const __bf16* hb, int kstart, int g) {
        GArgs ga;
        ga.G = aggG; ga.S = aggS; ga.Hb = hb; ga.A0 = Abuf;
        ga.Wt = Wt; ga.bc = bcv;
        for (int i = 0; i < 4; ++i) ga.tg[i] = targ[i];
        ga.slot = (long long)NCf;
        ga.nk = g;
        ga.initmask = 0;
        ga.shadow_t = -1;
        ga.shadow_ptr = hbuf[0];
        for (int j = 0; j < g; ++j) {
            int k = P.ks[kstart + j];
            ga.kidx[j] = k;
            ga.tsel[j] = P.tg[kstart + j];
            if (k == 0 || k == 2 || k == 5 || k == 9) ga.initmask |= (1 << j);
            if (k == 1) { ga.shadow_t = j; ga.shadow_ptr = hbuf[1]; }
            if (k == 4) { ga.shadow_t = j; ga.shadow_ptr = hbuf[2]; }
            if (k == 8) { ga.shadow_t = j; ga.shadow_ptr = hbuf[3]; }
        }
        for (int j = g; j < 8; ++j) { ga.kidx[j] = 0; ga.tsel[j] = (j > 0) ? ga.tsel[j - 1] : 0; }
        gemm_group<<<GEMM_GRID, 256, 0, stream>>>(ga);
    };

    for (int st = 0; st < 4; ++st) {
        const Phase& P = ph[st];
        const __bf16* hb = hbuf[st];
        score_mfma<<<GEMM_GRID, 256, 0, stream>>>(hb, Vph + st * 1024, ssrcS, sdstS);
        if (navail >= P.nk) {
            int done = 0;
            while (done < P.nk) {
                int g = P.nk - done;
                if (g > 4) g = 4;
                launch_gather(g, hb, done, (done == 0) ? 1 : 0, Abuf + (size_t)done * NCf);
                done += g;
            }
            make_gemm(P, hb, 0, P.nk);
        } else {
            int gs = (navail < 4) ? navail : 4;
            for (int done = 0; done < P.nk;) {
                int g = gs;
                if (g > P.nk - done) g = P.nk - done;
                launch_gather(g, hb, done, (done == 0) ? 1 : 0, Abuf);
                make_gemm(P, hb, done, g);
                done += g;
            }
        }
    }
}